// Round 1
// baseline (1043.370 us; speedup 1.0000x reference)
//
#include <hip/hip_runtime.h>
#include <math.h>

#define NN 50000
#define EE 800000
#define BBG 256
#define HHC 128

// ---------------- utility kernels ----------------

__global__ void zero4_kernel(float4* p, int n) {
  int i = blockIdx.x * 256 + threadIdx.x;
  if (i < n) p[i] = make_float4(0.f, 0.f, 0.f, 0.f);
}

__global__ void build_deg_kernel(const int* __restrict__ ei, int* __restrict__ deg) {
  int e = blockIdx.x * 256 + threadIdx.x;   // grid exact: 3125*256 = 800000
  atomicAdd(&deg[ei[EE + e]], 1);
}

__global__ void build_ghist_kernel(const int* __restrict__ batch, int* __restrict__ gc) {
  int i = blockIdx.x * 256 + threadIdx.x;
  if (i < NN) atomicAdd(&gc[batch[i]], 1);
}

// single-block exclusive scan; out has n+1 entries; cursor (optional) = copy of out[0..n)
__global__ void scan_kernel(const int* __restrict__ in, int* __restrict__ out,
                            int* __restrict__ cursor, int n) {
  __shared__ int buf[1024];
  int tid = threadIdx.x;
  int S = (n + 1023) >> 10;
  int lo = tid * S;
  int hi = lo + S; if (hi > n) hi = n;
  int sum = 0;
  for (int i = lo; i < hi; ++i) sum += in[i];
  buf[tid] = sum;
  __syncthreads();
  for (int off = 1; off < 1024; off <<= 1) {
    int t = (tid >= off) ? buf[tid - off] : 0;
    __syncthreads();
    buf[tid] += t;
    __syncthreads();
  }
  int run = buf[tid] - sum;  // exclusive prefix of this thread's chunk
  for (int i = lo; i < hi; ++i) {
    out[i] = run;
    if (cursor) cursor[i] = run;
    run += in[i];
  }
  if (tid == 1023) out[n] = buf[1023];
}

__global__ void scatter_kernel(const int* __restrict__ ei, int* __restrict__ cursor,
                               int* __restrict__ csr) {
  int e = blockIdx.x * 256 + threadIdx.x;   // exact grid
  int d = ei[EE + e];
  int pos = atomicAdd(&cursor[d], 1);
  csr[pos] = ei[e];
}

// ---------------- weight prep ----------------

// 4x 128x128: WT[m][k][o] = W[m][o][k]
__global__ void transpose_gin_kernel(const float* __restrict__ W0, const float* __restrict__ W1,
                                     const float* __restrict__ W2, const float* __restrict__ W3,
                                     float* __restrict__ WT) {
  int idx = blockIdx.x * 256 + threadIdx.x;  // 4*16384 = 65536 exact
  int m = idx >> 14;
  int r = idx & 16383;
  int k = r >> 7, o = r & 127;
  const float* W = (m == 0) ? W0 : (m == 1) ? W1 : (m == 2) ? W2 : W3;
  WT[idx] = W[o * 128 + k];
}

// WT0: [384][512] interleaved cols o'=4j+g ; k<256 from Wih0[g*128+j][k], else Whh0[..][k-256]
__global__ void build_wt0_kernel(const float* __restrict__ Wih0, const float* __restrict__ Whh0,
                                 float* __restrict__ WT0) {
  int idx = blockIdx.x * 256 + threadIdx.x;  // 384*512 = 196608 exact
  int k = idx >> 9, op = idx & 511;
  int j = op >> 2, g = op & 3;
  int row = g * 128 + j;
  float v = (k < 256) ? Wih0[row * 256 + k] : Whh0[row * 128 + (k - 256)];
  WT0[idx] = v;
}

// WTR: 3 layers of [256][512] interleaved
__global__ void build_wtr_kernel(const float* __restrict__ WihR, const float* __restrict__ WhhR,
                                 float* __restrict__ WTR) {
  int idx = blockIdx.x * 256 + threadIdx.x;  // 3*131072 = 393216 exact
  int l = idx >> 17;
  int rem = idx & 131071;
  int k = rem >> 9, op = rem & 511;
  int j = op >> 2, g = op & 3;
  int row = g * 128 + j;
  float v = (k < 128) ? WihR[((size_t)l * 512 + row) * 128 + k]
                      : WhhR[((size_t)l * 512 + row) * 128 + (k - 128)];
  WTR[idx] = v;
}

__global__ void build_bias_kernel(const float* __restrict__ b0, const float* __restrict__ bR,
                                  float* __restrict__ bc0, float* __restrict__ bcR) {
  int idx = blockIdx.x * 256 + threadIdx.x;  // 2048 exact
  if (idx < 512) {
    bc0[idx] = b0[(idx & 3) * 128 + (idx >> 2)];
  } else {
    int t = idx - 512;
    int l = t >> 9, op = t & 511;
    bcR[t] = bR[l * 512 + (op & 3) * 128 + (op >> 2)];
  }
}

// ---------------- GIN ----------------

// one wave per node: out[i] = x[i] + sum_{j in CSR(i)} x[j]
__global__ void gin_agg_kernel(const float* __restrict__ xin, const int* __restrict__ row_start,
                               const int* __restrict__ csr, float* __restrict__ outp) {
  int node = blockIdx.x * 4 + (threadIdx.x >> 6);  // exact: 12500*4 = 50000
  int lane = threadIdx.x & 63;
  const float2* x2 = (const float2*)xin;
  float2 acc = x2[(size_t)node * 64 + lane];       // self term (eps=0)
  int s0 = row_start[node], s1 = row_start[node + 1];
  for (int j = s0; j < s1; ++j) {
    int s = csr[j];
    float2 v = x2[(size_t)s * 64 + lane];
    acc.x += v.x; acc.y += v.y;
  }
  ((float2*)outp)[(size_t)node * 64 + lane] = acc;
}

// C[M,128] = A[M,128] @ W^T + b, with per-channel sum/sumsq atomics for BN.
// BM=64, BN=64, TM=4, TN=4. WT is k-major [128][128]. grid.x = 2*ceil(M/64)
__global__ __launch_bounds__(256) void gemm_gin_kernel(
    const float* __restrict__ A, const float* __restrict__ WT,
    const float* __restrict__ bias, float* __restrict__ C,
    float* __restrict__ ssum, float* __restrict__ ssq, int M) {
  __shared__ float As[64][132];
  __shared__ float Wt[128][68];
  int tid = threadIdx.x;
  int tx = tid & 15, ty = tid >> 4;
  int bx = blockIdx.x & 1, by = blockIdx.x >> 1;
  int row0 = by * 64, c0 = bx * 64;
#pragma unroll
  for (int i = 0; i < 8; ++i) {
    int slot = tid + i * 256;
    int r = slot >> 5, k4 = (slot & 31) << 2;
    float4 v = make_float4(0.f, 0.f, 0.f, 0.f);
    if (row0 + r < M) v = *(const float4*)(A + (size_t)(row0 + r) * 128 + k4);
    *(float4*)&As[r][k4] = v;
  }
#pragma unroll
  for (int i = 0; i < 8; ++i) {
    int slot = tid + i * 256;
    int k = slot >> 4, c4 = (slot & 15) << 2;
    *(float4*)&Wt[k][c4] = *(const float4*)(WT + (size_t)k * 128 + c0 + c4);
  }
  __syncthreads();
  float acc[4][4];
#pragma unroll
  for (int i = 0; i < 4; ++i)
#pragma unroll
    for (int j = 0; j < 4; ++j) acc[i][j] = 0.f;
#pragma unroll 4
  for (int kk = 0; kk < 128; kk += 4) {
    float4 w0 = *(const float4*)&Wt[kk + 0][tx << 2];
    float4 w1 = *(const float4*)&Wt[kk + 1][tx << 2];
    float4 w2 = *(const float4*)&Wt[kk + 2][tx << 2];
    float4 w3 = *(const float4*)&Wt[kk + 3][tx << 2];
#pragma unroll
    for (int i = 0; i < 4; ++i) {
      float4 a = *(const float4*)&As[(ty << 2) + i][kk];
      acc[i][0] += a.x * w0.x + a.y * w1.x + a.z * w2.x + a.w * w3.x;
      acc[i][1] += a.x * w0.y + a.y * w1.y + a.z * w2.y + a.w * w3.y;
      acc[i][2] += a.x * w0.z + a.y * w1.z + a.z * w2.z + a.w * w3.z;
      acc[i][3] += a.x * w0.w + a.y * w1.w + a.z * w2.w + a.w * w3.w;
    }
  }
  __syncthreads();
  float b0v = bias[c0 + (tx << 2) + 0];
  float b1v = bias[c0 + (tx << 2) + 1];
  float b2v = bias[c0 + (tx << 2) + 2];
  float b3v = bias[c0 + (tx << 2) + 3];
  float psum[4] = {0.f, 0.f, 0.f, 0.f}, psq[4] = {0.f, 0.f, 0.f, 0.f};
#pragma unroll
  for (int i = 0; i < 4; ++i) {
    int r = row0 + (ty << 2) + i;
    if (r < M) {
      float4 v;
      v.x = acc[i][0] + b0v; v.y = acc[i][1] + b1v;
      v.z = acc[i][2] + b2v; v.w = acc[i][3] + b3v;
      *(float4*)(C + (size_t)r * 128 + c0 + (tx << 2)) = v;
      psum[0] += v.x; psum[1] += v.y; psum[2] += v.z; psum[3] += v.w;
      psq[0] += v.x * v.x; psq[1] += v.y * v.y; psq[2] += v.z * v.z; psq[3] += v.w * v.w;
    }
  }
  float* red = &As[0][0];  // reuse LDS: 2*16*68 = 2176 floats
#pragma unroll
  for (int j = 0; j < 4; ++j) {
    red[ty * 68 + (tx << 2) + j] = psum[j];
    red[1088 + ty * 68 + (tx << 2) + j] = psq[j];
  }
  __syncthreads();
  if (tid < 64) {
    float s = 0.f, sq = 0.f;
#pragma unroll
    for (int t = 0; t < 16; ++t) { s += red[t * 68 + tid]; sq += red[1088 + t * 68 + tid]; }
    atomicAdd(&ssum[c0 + tid], s);
    atomicAdd(&ssq[c0 + tid], sq);
  }
}

__global__ void bn_finalize_kernel(const float* __restrict__ sums, const float* __restrict__ sqs,
                                   const float* __restrict__ gamma, const float* __restrict__ beta,
                                   float* __restrict__ scale, float* __restrict__ shift) {
  int c = threadIdx.x;  // 128
  const float invN = 1.0f / (float)NN;
  float m = sums[c] * invN;
  float v = sqs[c] * invN - m * m;
  float rs = rsqrtf(v + 1e-5f);
  float sc = gamma[c] * rs;
  scale[c] = sc;
  shift[c] = beta[c] - m * sc;
}

__global__ void affine_relu_kernel(float* __restrict__ h, const float* __restrict__ scale,
                                   const float* __restrict__ shift) {
  int idx = blockIdx.x * 256 + threadIdx.x;  // exact: 6250*256 = 1600000 float4s
  float4 v = ((float4*)h)[idx];
  int c = (idx & 31) << 2;
  v.x = fmaxf(fmaf(v.x, scale[c + 0], shift[c + 0]), 0.f);
  v.y = fmaxf(fmaf(v.y, scale[c + 1], shift[c + 1]), 0.f);
  v.z = fmaxf(fmaf(v.z, scale[c + 2], shift[c + 2]), 0.f);
  v.w = fmaxf(fmaf(v.w, scale[c + 3], shift[c + 3]), 0.f);
  ((float4*)h)[idx] = v;
}

// ---------------- Set2Set ----------------

// Fused gate-GEMM + LSTM pointwise. A = concat(inA[pitchA, splitK], inB[256x128]).
// WT: [K][512] gate-interleaved (col 4j+g). BM=16,BN=64,TM=1,TN=4. grid (8,16).
__global__ __launch_bounds__(256) void lstm_cell_kernel(
    const float* __restrict__ inA, int pitchA, int splitK,
    const float* __restrict__ inB,
    const float* __restrict__ WT, const float* __restrict__ bias,
    float* __restrict__ cstate, float* __restrict__ hout, int K) {
  __shared__ float As[16][132];
  __shared__ float Wt[128][68];
  int tid = threadIdx.x;
  int tx = tid & 15, ty = tid >> 4;
  int bx = blockIdx.x, by = blockIdx.y;
  int row0 = by * 16, c0 = bx * 64;
  float acc[4] = {0.f, 0.f, 0.f, 0.f};
  for (int kc = 0; kc < K; kc += 128) {
#pragma unroll
    for (int i = 0; i < 2; ++i) {
      int slot = tid + i * 256;
      int r = slot >> 5, k4 = (slot & 31) << 2;
      int gc = kc + k4;
      const float* src = (gc < splitK) ? inA + (size_t)(row0 + r) * pitchA + gc
                                       : inB + (size_t)(row0 + r) * 128 + (gc - splitK);
      *(float4*)&As[r][k4] = *(const float4*)src;
    }
#pragma unroll
    for (int i = 0; i < 8; ++i) {
      int slot = tid + i * 256;
      int k = slot >> 4, c4 = (slot & 15) << 2;
      *(float4*)&Wt[k][c4] = *(const float4*)(WT + (size_t)(kc + k) * 512 + c0 + c4);
    }
    __syncthreads();
#pragma unroll 4
    for (int kk = 0; kk < 128; kk += 4) {
      float4 a = *(const float4*)&As[ty][kk];
      float4 w0 = *(const float4*)&Wt[kk + 0][tx << 2];
      float4 w1 = *(const float4*)&Wt[kk + 1][tx << 2];
      float4 w2 = *(const float4*)&Wt[kk + 2][tx << 2];
      float4 w3 = *(const float4*)&Wt[kk + 3][tx << 2];
      acc[0] += a.x * w0.x + a.y * w1.x + a.z * w2.x + a.w * w3.x;
      acc[1] += a.x * w0.y + a.y * w1.y + a.z * w2.y + a.w * w3.y;
      acc[2] += a.x * w0.z + a.y * w1.z + a.z * w2.z + a.w * w3.z;
      acc[3] += a.x * w0.w + a.y * w1.w + a.z * w2.w + a.w * w3.w;
    }
    __syncthreads();
  }
  int b = row0 + ty;
  int j = bx * 16 + tx;
  int ob = c0 + (tx << 2);
  float ii = acc[0] + bias[ob + 0];
  float ff = acc[1] + bias[ob + 1];
  float gg = acc[2] + bias[ob + 2];
  float oo = acc[3] + bias[ob + 3];
  float cp = cstate[b * 128 + j];
  float si = 1.f / (1.f + expf(-ii));
  float sf = 1.f / (1.f + expf(-ff));
  float so = 1.f / (1.f + expf(-oo));
  float cn = sf * cp + si * tanhf(gg);
  float hv = so * tanhf(cn);
  cstate[b * 128 + j] = cn;
  hout[b * 128 + j] = hv;
}

// per-graph segment softmax attention; writes q_star[g] = [q | r] (pitch 256)
__global__ __launch_bounds__(256) void attention_kernel(
    const float* __restrict__ x, const int* __restrict__ gptr,
    const float* __restrict__ h3, float* __restrict__ ebuf, float* __restrict__ qstar) {
  int g = blockIdx.x;
  int tid = threadIdx.x;
  int lane = tid & 63, w = tid >> 6;
  __shared__ float q[128];
  __shared__ float wred[4];
  __shared__ float rpart[4][128];
  __shared__ float sm, ssv;
  if (tid < 128) q[tid] = h3[g * 128 + tid];
  __syncthreads();
  int s0 = gptr[g], s1 = gptr[g + 1];
  const float2* x2 = (const float2*)x;
  float2 qv = ((const float2*)q)[lane];
  // pass 1: e + max
  float wmax = -3.0e38f;
  for (int n = s0 + w; n < s1; n += 4) {
    float2 v = x2[(size_t)n * 64 + lane];
    float e = v.x * qv.x + v.y * qv.y;
#pragma unroll
    for (int sh = 32; sh; sh >>= 1) e += __shfl_xor(e, sh);
    if (lane == 0) ebuf[n] = e;
    wmax = fmaxf(wmax, e);
  }
  if (lane == 0) wred[w] = wmax;
  __syncthreads();
  if (tid == 0) sm = fmaxf(fmaxf(wred[0], wred[1]), fmaxf(wred[2], wred[3]));
  __syncthreads();
  float m = sm;
  // pass 2: sum exp
  float loc = 0.f;
  for (int n = s0 + tid; n < s1; n += 256) loc += expf(ebuf[n] - m);
#pragma unroll
  for (int sh = 32; sh; sh >>= 1) loc += __shfl_xor(loc, sh);
  __syncthreads();
  if (lane == 0) wred[w] = loc;
  __syncthreads();
  if (tid == 0) ssv = wred[0] + wred[1] + wred[2] + wred[3];
  __syncthreads();
  float inv = 1.0f / ssv;
  // pass 3: r = sum a*x
  float rx = 0.f, ry = 0.f;
  for (int n = s0 + w; n < s1; n += 4) {
    float coef = expf(ebuf[n] - m) * inv;
    float2 v = x2[(size_t)n * 64 + lane];
    rx += coef * v.x; ry += coef * v.y;
  }
  rpart[w][2 * lane] = rx;
  rpart[w][2 * lane + 1] = ry;
  __syncthreads();
  if (tid < 128) {
    float r = rpart[0][tid] + rpart[1][tid] + rpart[2][tid] + rpart[3][tid];
    qstar[(size_t)g * 256 + tid] = q[tid];
    qstar[(size_t)g * 256 + 128 + tid] = r;
  }
}

__global__ void final_linear_kernel(const float* __restrict__ qstar, const float* __restrict__ WL,
                                    const float* __restrict__ bL, float* __restrict__ out) {
  int g = blockIdx.x;
  int lane = threadIdx.x;  // 64
  float a0 = 0.f, a1 = 0.f;
  for (int k = lane; k < 256; k += 64) {
    float qv = qstar[(size_t)g * 256 + k];
    a0 += qv * WL[k];
    a1 += qv * WL[256 + k];
  }
#pragma unroll
  for (int sh = 32; sh; sh >>= 1) {
    a0 += __shfl_xor(a0, sh);
    a1 += __shfl_xor(a1, sh);
  }
  if (lane == 0) {
    out[2 * g + 0] = a0 + bL[0];
    out[2 * g + 1] = a1 + bL[1];
  }
}

// ---------------- launch ----------------

extern "C" void kernel_launch(void* const* d_in, const int* in_sizes, int n_in,
                              void* d_out, int out_size, void* d_ws, size_t ws_size,
                              hipStream_t stream) {
  const float* x = (const float*)d_in[0];
  const int* ei = (const int*)d_in[1];
  const int* batch = (const int*)d_in[2];
  const float* gW[4]  = {(const float*)d_in[3],  (const float*)d_in[7],
                         (const float*)d_in[11], (const float*)d_in[15]};
  const float* gb[4]  = {(const float*)d_in[4],  (const float*)d_in[8],
                         (const float*)d_in[12], (const float*)d_in[16]};
  const float* gga[4] = {(const float*)d_in[5],  (const float*)d_in[9],
                         (const float*)d_in[13], (const float*)d_in[17]};
  const float* gbe[4] = {(const float*)d_in[6],  (const float*)d_in[10],
                         (const float*)d_in[14], (const float*)d_in[18]};
  const float* Wih0 = (const float*)d_in[19];
  const float* Whh0 = (const float*)d_in[20];
  const float* b0   = (const float*)d_in[21];
  const float* WihR = (const float*)d_in[22];
  const float* WhhR = (const float*)d_in[23];
  const float* bR   = (const float*)d_in[24];
  const float* linW = (const float*)d_in[25];
  const float* linb = (const float*)d_in[26];
  float* out = (float*)d_out;

  char* base = (char*)d_ws;
  size_t off = 0;
  auto allocf = [&](size_t n) { float* p = (float*)(base + off); off += n * sizeof(float); return p; };
  float* xa    = allocf(6400000);
  float* xb    = allocf(6400000);
  float* ginWT = allocf(65536);    // 4 x [128][128] k-major
  float* WT0   = allocf(196608);   // [384][512]
  float* WTR   = allocf(393216);   // 3 x [256][512]
  float* bc0   = allocf(512);
  float* bcR   = allocf(1536);
  float* ebuf  = allocf(50000);
  float* zb    = (float*)(base + off);  // ---- zero region (floats) ----
  float* stats = allocf(1024);     // 4 x (sum128|sq128)
  float* sshf  = allocf(1024);     // 4 x (scale128|shift128)
  float* cbuf  = allocf(131072);   // 4 x 256x128
  float* hbuf  = allocf(262144);   // [4][2][256x128]
  float* qstar = allocf(65536);    // 256x256
  // ---- int region; deg+gcount zeroed ----
  int* deg = (int*)(base + off); off += 50000 * 4;
  int* gcount = (int*)(base + off); off += 256 * 4;
  int* row_start = (int*)(base + off); off += 50004 * 4;
  int* cursor = (int*)(base + off); off += 50000 * 4;
  int* gptr = (int*)(base + off); off += 260 * 4;
  int* csr = (int*)(base + off); off += 800000 * 4;
  (void)ws_size; (void)in_sizes; (void)n_in; (void)out_size;

  // prep
  zero4_kernel<<<450, 256, 0, stream>>>((float4*)zb, 115200);       // 460800 floats
  zero4_kernel<<<50, 256, 0, stream>>>((float4*)deg, 12564);        // 50256 ints
  build_deg_kernel<<<3125, 256, 0, stream>>>(ei, deg);
  build_ghist_kernel<<<196, 256, 0, stream>>>(batch, gcount);
  scan_kernel<<<1, 1024, 0, stream>>>(deg, row_start, cursor, 50000);
  scan_kernel<<<1, 1024, 0, stream>>>(gcount, gptr, nullptr, 256);
  scatter_kernel<<<3125, 256, 0, stream>>>(ei, cursor, csr);
  transpose_gin_kernel<<<256, 256, 0, stream>>>(gW[0], gW[1], gW[2], gW[3], ginWT);
  build_wt0_kernel<<<768, 256, 0, stream>>>(Wih0, Whh0, WT0);
  build_wtr_kernel<<<1536, 256, 0, stream>>>(WihR, WhhR, WTR);
  build_bias_kernel<<<8, 256, 0, stream>>>(b0, bR, bc0, bcR);

  // GIN layer 1
  gin_agg_kernel<<<12500, 256, 0, stream>>>(x, row_start, csr, xb);
  gemm_gin_kernel<<<1564, 256, 0, stream>>>(xb, ginWT + 0 * 16384, gb[0], xa, stats + 0, stats + 128, 50000);
  bn_finalize_kernel<<<1, 128, 0, stream>>>(stats + 0, stats + 128, gga[0], gbe[0], sshf + 0, sshf + 128);
  affine_relu_kernel<<<6250, 256, 0, stream>>>(xa, sshf + 0, sshf + 128);
  gemm_gin_kernel<<<1564, 256, 0, stream>>>(xa, ginWT + 1 * 16384, gb[1], xb, stats + 256, stats + 384, 50000);
  bn_finalize_kernel<<<1, 128, 0, stream>>>(stats + 256, stats + 384, gga[1], gbe[1], sshf + 256, sshf + 384);
  affine_relu_kernel<<<6250, 256, 0, stream>>>(xb, sshf + 256, sshf + 384);
  // GIN layer 2
  gin_agg_kernel<<<12500, 256, 0, stream>>>(xb, row_start, csr, xa);
  gemm_gin_kernel<<<1564, 256, 0, stream>>>(xa, ginWT + 2 * 16384, gb[2], xb, stats + 512, stats + 640, 50000);
  bn_finalize_kernel<<<1, 128, 0, stream>>>(stats + 512, stats + 640, gga[2], gbe[2], sshf + 512, sshf + 640);
  affine_relu_kernel<<<6250, 256, 0, stream>>>(xb, sshf + 512, sshf + 640);
  gemm_gin_kernel<<<1564, 256, 0, stream>>>(xb, ginWT + 3 * 16384, gb[3], xa, stats + 768, stats + 896, 50000);
  bn_finalize_kernel<<<1, 128, 0, stream>>>(stats + 768, stats + 896, gga[3], gbe[3], sshf + 768, sshf + 896);
  affine_relu_kernel<<<6250, 256, 0, stream>>>(xa, sshf + 768, sshf + 896);
  // final node features in xa

  // Set2Set
  dim3 lg(8, 16);
  for (int step = 0; step < 4; ++step) {
    int p = step & 1, pq = 1 - p;
    float* h0r = hbuf + (size_t)(0 * 2 + p) * 32768;  float* h0w = hbuf + (size_t)(0 * 2 + pq) * 32768;
    float* h1r = hbuf + (size_t)(1 * 2 + p) * 32768;  float* h1w = hbuf + (size_t)(1 * 2 + pq) * 32768;
    float* h2r = hbuf + (size_t)(2 * 2 + p) * 32768;  float* h2w = hbuf + (size_t)(2 * 2 + pq) * 32768;
    float* h3r = hbuf + (size_t)(3 * 2 + p) * 32768;  float* h3w = hbuf + (size_t)(3 * 2 + pq) * 32768;
    lstm_cell_kernel<<<lg, 256, 0, stream>>>(qstar, 256, 256, h0r, WT0, bc0, cbuf + 0, h0w, 384);
    lstm_cell_kernel<<<lg, 256, 0, stream>>>(h0w, 128, 128, h1r, WTR + 0, bcR + 0, cbuf + 32768, h1w, 256);
    lstm_cell_kernel<<<lg, 256, 0, stream>>>(h1w, 128, 128, h2r, WTR + 131072, bcR + 512, cbuf + 65536, h2w, 256);
    lstm_cell_kernel<<<lg, 256, 0, stream>>>(h2w, 128, 128, h3r, WTR + 262144, bcR + 1024, cbuf + 98304, h3w, 256);
    attention_kernel<<<256, 256, 0, stream>>>(xa, gptr, h3w, ebuf, qstar);
  }
  final_linear_kernel<<<256, 64, 0, stream>>>(qstar, linW, linb, out);
}

// Round 2
// 949.261 us; speedup vs baseline: 1.0991x; 1.0991x over previous
//
#include <hip/hip_runtime.h>
#include <math.h>

#define NN 50000
#define EE 800000
#define BBG 256
#define HHC 128
#define SEG_CAP 240

// ---------------- utility kernels ----------------

__global__ void zero4_kernel(float4* p, int n) {
  int i = blockIdx.x * 256 + threadIdx.x;
  if (i < n) p[i] = make_float4(0.f, 0.f, 0.f, 0.f);
}

// edges -> deg histogram, nodes -> graph histogram, one kernel
__global__ void combined_hist_kernel(const int* __restrict__ ei, const int* __restrict__ batch,
                                     int* __restrict__ deg, int* __restrict__ gc) {
  int i = blockIdx.x * 256 + threadIdx.x;
  if (i < EE) {
    atomicAdd(&deg[ei[EE + i]], 1);
  } else if (i < EE + NN) {
    atomicAdd(&gc[batch[i - EE]], 1);
  }
}

// ---- multi-block scan over deg[50000] ----
__global__ void chunk_sum_kernel(const int* __restrict__ in, int* __restrict__ bsum, int n) {
  int b = blockIdx.x, tid = threadIdx.x;
  int i = b * 256 + tid;
  int v = (i < n) ? in[i] : 0;
#pragma unroll
  for (int sh = 32; sh; sh >>= 1) v += __shfl_xor(v, sh);
  __shared__ int ws[4];
  if ((tid & 63) == 0) ws[tid >> 6] = v;
  __syncthreads();
  if (tid == 0) bsum[b] = ws[0] + ws[1] + ws[2] + ws[3];
}

__global__ void scan_bsum_kernel(const int* __restrict__ bsum, int* __restrict__ boff, int nb) {
  __shared__ int buf[256];
  int tid = threadIdx.x;
  int v = (tid < nb) ? bsum[tid] : 0;
  buf[tid] = v;
  __syncthreads();
  for (int off = 1; off < 256; off <<= 1) {
    int t = (tid >= off) ? buf[tid - off] : 0;
    __syncthreads();
    buf[tid] += t;
    __syncthreads();
  }
  if (tid < nb) boff[tid] = buf[tid] - v;  // exclusive
}

__global__ void chunk_scan_kernel(const int* __restrict__ in, const int* __restrict__ boff,
                                  int* __restrict__ out, int* __restrict__ cursor, int n) {
  __shared__ int buf[256];
  int b = blockIdx.x, tid = threadIdx.x;
  int i = b * 256 + tid;
  int v = (i < n) ? in[i] : 0;
  buf[tid] = v;
  __syncthreads();
  for (int off = 1; off < 256; off <<= 1) {
    int t = (tid >= off) ? buf[tid - off] : 0;
    __syncthreads();
    buf[tid] += t;
    __syncthreads();
  }
  int excl = buf[tid] - v + boff[b];
  if (i < n) {
    out[i] = excl;
    cursor[i] = excl;
    if (i == n - 1) out[n] = excl + v;
  }
}

// single block scan of exactly 256 values -> out[257]
__global__ void scan256_kernel(const int* __restrict__ in, int* __restrict__ out) {
  __shared__ int buf[256];
  int tid = threadIdx.x;
  int v = in[tid];
  buf[tid] = v;
  __syncthreads();
  for (int off = 1; off < 256; off <<= 1) {
    int t = (tid >= off) ? buf[tid - off] : 0;
    __syncthreads();
    buf[tid] += t;
    __syncthreads();
  }
  out[tid] = buf[tid] - v;
  if (tid == 255) out[256] = buf[255];
}

__global__ void scatter_kernel(const int* __restrict__ ei, int* __restrict__ cursor,
                               int* __restrict__ csr) {
  int e = blockIdx.x * 256 + threadIdx.x;   // exact grid
  int d = ei[EE + e];
  int pos = atomicAdd(&cursor[d], 1);
  csr[pos] = ei[e];
}

// ---------------- weight prep (single kernel) ----------------
// [0,65536): ginWT (4x 128x128 k-major)   [65536,262144): WT0 [384][512]
// [262144,655360): WTR 3x[256][512]       [655360,657408): biases
__global__ void prep_weights_kernel(const float* __restrict__ W0, const float* __restrict__ W1,
                                    const float* __restrict__ W2, const float* __restrict__ W3,
                                    const float* __restrict__ Wih0, const float* __restrict__ Whh0,
                                    const float* __restrict__ WihR, const float* __restrict__ WhhR,
                                    const float* __restrict__ b0, const float* __restrict__ bR,
                                    float* __restrict__ ginWT, float* __restrict__ WT0,
                                    float* __restrict__ WTR, float* __restrict__ bc0,
                                    float* __restrict__ bcR) {
  int idx = blockIdx.x * 256 + threadIdx.x;  // grid 2568*256 = 657408 exact
  if (idx < 65536) {
    int m = idx >> 14;
    int r = idx & 16383;
    int k = r >> 7, o = r & 127;
    const float* W = (m == 0) ? W0 : (m == 1) ? W1 : (m == 2) ? W2 : W3;
    ginWT[idx] = W[o * 128 + k];
  } else if (idx < 262144) {
    int t = idx - 65536;
    int k = t >> 9, op = t & 511;
    int j = op >> 2, g = op & 3;
    int row = g * 128 + j;
    WT0[t] = (k < 256) ? Wih0[row * 256 + k] : Whh0[row * 128 + (k - 256)];
  } else if (idx < 655360) {
    int t = idx - 262144;
    int l = t >> 17;
    int rem = t & 131071;
    int k = rem >> 9, op = rem & 511;
    int j = op >> 2, g = op & 3;
    int row = g * 128 + j;
    WTR[t] = (k < 128) ? WihR[((size_t)l * 512 + row) * 128 + k]
                       : WhhR[((size_t)l * 512 + row) * 128 + (k - 128)];
  } else {
    int t = idx - 655360;
    if (t < 512) {
      bc0[t] = b0[(t & 3) * 128 + (t >> 2)];
    } else {
      int u = t - 512;
      int l = u >> 9, op = u & 511;
      bcR[u] = bR[l * 512 + (op & 3) * 128 + (op >> 2)];
    }
  }
}

// ---------------- GIN ----------------

// one wave per node: out[i] = f(x[i]) + sum_{j in CSR(i)} f(x[j]),
// f = optional per-channel affine+relu (fused BN of the previous layer)
__global__ void gin_agg_kernel(const float* __restrict__ xin, const int* __restrict__ row_start,
                               const int* __restrict__ csr,
                               const float* __restrict__ pre_scale,
                               const float* __restrict__ pre_shift,
                               float* __restrict__ outp) {
  int node = blockIdx.x * 4 + (threadIdx.x >> 6);  // exact: 12500*4 = 50000
  int lane = threadIdx.x & 63;
  const float2* x2 = (const float2*)xin;
  int s0 = row_start[node], s1 = row_start[node + 1];
  float2 acc;
  if (pre_scale) {
    float sc0 = pre_scale[2 * lane], sc1 = pre_scale[2 * lane + 1];
    float sh0 = pre_shift[2 * lane], sh1 = pre_shift[2 * lane + 1];
    float2 s = x2[(size_t)node * 64 + lane];
    acc.x = fmaxf(fmaf(s.x, sc0, sh0), 0.f);
    acc.y = fmaxf(fmaf(s.y, sc1, sh1), 0.f);
    for (int j = s0; j < s1; ++j) {
      float2 v = x2[(size_t)csr[j] * 64 + lane];
      acc.x += fmaxf(fmaf(v.x, sc0, sh0), 0.f);
      acc.y += fmaxf(fmaf(v.y, sc1, sh1), 0.f);
    }
  } else {
    acc = x2[(size_t)node * 64 + lane];
    for (int j = s0; j < s1; ++j) {
      float2 v = x2[(size_t)csr[j] * 64 + lane];
      acc.x += v.x;
      acc.y += v.y;
    }
  }
  ((float2*)outp)[(size_t)node * 64 + lane] = acc;
}

// C[M,128] = f(A)[M,128] @ W^T + b, f = optional affine+relu on A columns.
// Per-channel sum/sumsq atomics for the following BN.
// BM=64, BN=64, TM=4, TN=4. WT is k-major [128][128]. grid.x = 2*ceil(M/64)
__global__ __launch_bounds__(256) void gemm_gin_kernel(
    const float* __restrict__ A, const float* __restrict__ WT,
    const float* __restrict__ bias,
    const float* __restrict__ pre_scale, const float* __restrict__ pre_shift,
    float* __restrict__ C,
    float* __restrict__ ssum, float* __restrict__ ssq, int M) {
  __shared__ float As[64][132];
  __shared__ float Wt[128][68];
  int tid = threadIdx.x;
  int tx = tid & 15, ty = tid >> 4;
  int bx = blockIdx.x & 1, by = blockIdx.x >> 1;
  int row0 = by * 64, c0 = bx * 64;
#pragma unroll
  for (int i = 0; i < 8; ++i) {
    int slot = tid + i * 256;
    int r = slot >> 5, k4 = (slot & 31) << 2;
    float4 v = make_float4(0.f, 0.f, 0.f, 0.f);
    if (row0 + r < M) v = *(const float4*)(A + (size_t)(row0 + r) * 128 + k4);
    if (pre_scale) {
      v.x = fmaxf(fmaf(v.x, pre_scale[k4 + 0], pre_shift[k4 + 0]), 0.f);
      v.y = fmaxf(fmaf(v.y, pre_scale[k4 + 1], pre_shift[k4 + 1]), 0.f);
      v.z = fmaxf(fmaf(v.z, pre_scale[k4 + 2], pre_shift[k4 + 2]), 0.f);
      v.w = fmaxf(fmaf(v.w, pre_scale[k4 + 3], pre_shift[k4 + 3]), 0.f);
    }
    *(float4*)&As[r][k4] = v;
  }
#pragma unroll
  for (int i = 0; i < 8; ++i) {
    int slot = tid + i * 256;
    int k = slot >> 4, c4 = (slot & 15) << 2;
    *(float4*)&Wt[k][c4] = *(const float4*)(WT + (size_t)k * 128 + c0 + c4);
  }
  __syncthreads();
  float acc[4][4];
#pragma unroll
  for (int i = 0; i < 4; ++i)
#pragma unroll
    for (int j = 0; j < 4; ++j) acc[i][j] = 0.f;
#pragma unroll 4
  for (int kk = 0; kk < 128; kk += 4) {
    float4 w0 = *(const float4*)&Wt[kk + 0][tx << 2];
    float4 w1 = *(const float4*)&Wt[kk + 1][tx << 2];
    float4 w2 = *(const float4*)&Wt[kk + 2][tx << 2];
    float4 w3 = *(const float4*)&Wt[kk + 3][tx << 2];
#pragma unroll
    for (int i = 0; i < 4; ++i) {
      float4 a = *(const float4*)&As[(ty << 2) + i][kk];
      acc[i][0] += a.x * w0.x + a.y * w1.x + a.z * w2.x + a.w * w3.x;
      acc[i][1] += a.x * w0.y + a.y * w1.y + a.z * w2.y + a.w * w3.y;
      acc[i][2] += a.x * w0.z + a.y * w1.z + a.z * w2.z + a.w * w3.z;
      acc[i][3] += a.x * w0.w + a.y * w1.w + a.z * w2.w + a.w * w3.w;
    }
  }
  __syncthreads();
  float b0v = bias[c0 + (tx << 2) + 0];
  float b1v = bias[c0 + (tx << 2) + 1];
  float b2v = bias[c0 + (tx << 2) + 2];
  float b3v = bias[c0 + (tx << 2) + 3];
  float psum[4] = {0.f, 0.f, 0.f, 0.f}, psq[4] = {0.f, 0.f, 0.f, 0.f};
#pragma unroll
  for (int i = 0; i < 4; ++i) {
    int r = row0 + (ty << 2) + i;
    if (r < M) {
      float4 v;
      v.x = acc[i][0] + b0v; v.y = acc[i][1] + b1v;
      v.z = acc[i][2] + b2v; v.w = acc[i][3] + b3v;
      *(float4*)(C + (size_t)r * 128 + c0 + (tx << 2)) = v;
      psum[0] += v.x; psum[1] += v.y; psum[2] += v.z; psum[3] += v.w;
      psq[0] += v.x * v.x; psq[1] += v.y * v.y; psq[2] += v.z * v.z; psq[3] += v.w * v.w;
    }
  }
  float* red = &As[0][0];  // reuse LDS
#pragma unroll
  for (int j = 0; j < 4; ++j) {
    red[ty * 68 + (tx << 2) + j] = psum[j];
    red[1088 + ty * 68 + (tx << 2) + j] = psq[j];
  }
  __syncthreads();
  if (tid < 64) {
    float s = 0.f, sq = 0.f;
#pragma unroll
    for (int t = 0; t < 16; ++t) { s += red[t * 68 + tid]; sq += red[1088 + t * 68 + tid]; }
    atomicAdd(&ssum[c0 + tid], s);
    atomicAdd(&ssq[c0 + tid], sq);
  }
}

__global__ void bn_finalize_kernel(const float* __restrict__ sums, const float* __restrict__ sqs,
                                   const float* __restrict__ gamma, const float* __restrict__ beta,
                                   float* __restrict__ scale, float* __restrict__ shift) {
  int c = threadIdx.x;  // 128
  const float invN = 1.0f / (float)NN;
  float m = sums[c] * invN;
  float v = sqs[c] * invN - m * m;
  float rs = rsqrtf(v + 1e-5f);
  float sc = gamma[c] * rs;
  scale[c] = sc;
  shift[c] = beta[c] - m * sc;
}

__global__ void affine_relu_kernel(float* __restrict__ h, const float* __restrict__ scale,
                                   const float* __restrict__ shift) {
  int idx = blockIdx.x * 256 + threadIdx.x;  // exact: 6250*256 = 1600000 float4s
  float4 v = ((float4*)h)[idx];
  int c = (idx & 31) << 2;
  v.x = fmaxf(fmaf(v.x, scale[c + 0], shift[c + 0]), 0.f);
  v.y = fmaxf(fmaf(v.y, scale[c + 1], shift[c + 1]), 0.f);
  v.z = fmaxf(fmaf(v.z, scale[c + 2], shift[c + 2]), 0.f);
  v.w = fmaxf(fmaf(v.w, scale[c + 3], shift[c + 3]), 0.f);
  ((float4*)h)[idx] = v;
}

// ---------------- Set2Set ----------------

// Fused gate-GEMM + LSTM pointwise. A = concat(inA[pitchA, splitK], inB[256x128]).
// WT: [K][512] gate-interleaved (col 4j+g). BM=16,BN=64,TM=1,TN=4. grid (8,16).
__global__ __launch_bounds__(256) void lstm_cell_kernel(
    const float* __restrict__ inA, int pitchA, int splitK,
    const float* __restrict__ inB,
    const float* __restrict__ WT, const float* __restrict__ bias,
    float* __restrict__ cstate, float* __restrict__ hout, int K) {
  __shared__ float As[16][132];
  __shared__ float Wt[128][68];
  int tid = threadIdx.x;
  int tx = tid & 15, ty = tid >> 4;
  int bx = blockIdx.x, by = blockIdx.y;
  int row0 = by * 16, c0 = bx * 64;
  float acc[4] = {0.f, 0.f, 0.f, 0.f};
  for (int kc = 0; kc < K; kc += 128) {
#pragma unroll
    for (int i = 0; i < 2; ++i) {
      int slot = tid + i * 256;
      int r = slot >> 5, k4 = (slot & 31) << 2;
      int gc = kc + k4;
      const float* src = (gc < splitK) ? inA + (size_t)(row0 + r) * pitchA + gc
                                       : inB + (size_t)(row0 + r) * 128 + (gc - splitK);
      *(float4*)&As[r][k4] = *(const float4*)src;
    }
#pragma unroll
    for (int i = 0; i < 8; ++i) {
      int slot = tid + i * 256;
      int k = slot >> 4, c4 = (slot & 15) << 2;
      *(float4*)&Wt[k][c4] = *(const float4*)(WT + (size_t)(kc + k) * 512 + c0 + c4);
    }
    __syncthreads();
#pragma unroll 4
    for (int kk = 0; kk < 128; kk += 4) {
      float4 a = *(const float4*)&As[ty][kk];
      float4 w0 = *(const float4*)&Wt[kk + 0][tx << 2];
      float4 w1 = *(const float4*)&Wt[kk + 1][tx << 2];
      float4 w2 = *(const float4*)&Wt[kk + 2][tx << 2];
      float4 w3 = *(const float4*)&Wt[kk + 3][tx << 2];
      acc[0] += a.x * w0.x + a.y * w1.x + a.z * w2.x + a.w * w3.x;
      acc[1] += a.x * w0.y + a.y * w1.y + a.z * w2.y + a.w * w3.y;
      acc[2] += a.x * w0.z + a.y * w1.z + a.z * w2.z + a.w * w3.z;
      acc[3] += a.x * w0.w + a.y * w1.w + a.z * w2.w + a.w * w3.w;
    }
    __syncthreads();
  }
  int b = row0 + ty;
  int j = bx * 16 + tx;
  int ob = c0 + (tx << 2);
  float ii = acc[0] + bias[ob + 0];
  float ff = acc[1] + bias[ob + 1];
  float gg = acc[2] + bias[ob + 2];
  float oo = acc[3] + bias[ob + 3];
  float cp = cstate[b * 128 + j];
  float si = 1.f / (1.f + expf(-ii));
  float sf = 1.f / (1.f + expf(-ff));
  float so = 1.f / (1.f + expf(-oo));
  float cn = sf * cp + si * tanhf(gg);
  float hv = so * tanhf(cn);
  cstate[b * 128 + j] = cn;
  hout[b * 128 + j] = hv;
}

// per-graph segment softmax attention; caches the segment's x rows in LDS
// (global fallback for segments > SEG_CAP). Writes q_star[g] = [q | r].
__global__ __launch_bounds__(256) void attention_kernel(
    const float* __restrict__ x, const int* __restrict__ gptr,
    const float* __restrict__ h3, float* __restrict__ ebuf, float* __restrict__ qstar) {
  int g = blockIdx.x;
  int tid = threadIdx.x;
  int lane = tid & 63, w = tid >> 6;
  __shared__ float xs[SEG_CAP * 128];
  __shared__ float es[SEG_CAP];
  __shared__ float q[128];
  __shared__ float wred[4];
  __shared__ float rpart[4][128];
  __shared__ float sm, ssv;
  if (tid < 128) q[tid] = h3[g * 128 + tid];
  __syncthreads();
  int s0 = gptr[g], s1 = gptr[g + 1];
  bool fit = (s1 - s0) <= SEG_CAP;
  const float2* x2 = (const float2*)x;
  float2 qv = ((const float2*)q)[lane];
  // pass 1: e + max (stage x into LDS)
  float wmax = -3.0e38f;
  for (int n = s0 + w; n < s1; n += 4) {
    float2 v = x2[(size_t)n * 64 + lane];
    if (fit) {
      xs[(n - s0) * 128 + 2 * lane] = v.x;
      xs[(n - s0) * 128 + 2 * lane + 1] = v.y;
    }
    float e = v.x * qv.x + v.y * qv.y;
#pragma unroll
    for (int sh = 32; sh; sh >>= 1) e += __shfl_xor(e, sh);
    if (lane == 0) { if (fit) es[n - s0] = e; else ebuf[n] = e; }
    wmax = fmaxf(wmax, e);
  }
  if (lane == 0) wred[w] = wmax;
  __syncthreads();
  if (tid == 0) sm = fmaxf(fmaxf(wred[0], wred[1]), fmaxf(wred[2], wred[3]));
  __syncthreads();
  float m = sm;
  // pass 2: sum exp
  float loc = 0.f;
  for (int n = s0 + tid; n < s1; n += 256) {
    float e = fit ? es[n - s0] : ebuf[n];
    loc += expf(e - m);
  }
#pragma unroll
  for (int sh = 32; sh; sh >>= 1) loc += __shfl_xor(loc, sh);
  __syncthreads();
  if (lane == 0) wred[w] = loc;
  __syncthreads();
  if (tid == 0) ssv = wred[0] + wred[1] + wred[2] + wred[3];
  __syncthreads();
  float inv = 1.0f / ssv;
  // pass 3: r = sum a*x (from LDS when cached)
  float rx = 0.f, ry = 0.f;
  for (int n = s0 + w; n < s1; n += 4) {
    float e = fit ? es[n - s0] : ebuf[n];
    float coef = expf(e - m) * inv;
    float vx, vy;
    if (fit) {
      vx = xs[(n - s0) * 128 + 2 * lane];
      vy = xs[(n - s0) * 128 + 2 * lane + 1];
    } else {
      float2 v = x2[(size_t)n * 64 + lane];
      vx = v.x; vy = v.y;
    }
    rx += coef * vx; ry += coef * vy;
  }
  rpart[w][2 * lane] = rx;
  rpart[w][2 * lane + 1] = ry;
  __syncthreads();
  if (tid < 128) {
    float r = rpart[0][tid] + rpart[1][tid] + rpart[2][tid] + rpart[3][tid];
    qstar[(size_t)g * 256 + tid] = q[tid];
    qstar[(size_t)g * 256 + 128 + tid] = r;
  }
}

__global__ void final_linear_kernel(const float* __restrict__ qstar, const float* __restrict__ WL,
                                    const float* __restrict__ bL, float* __restrict__ out) {
  int g = blockIdx.x;
  int lane = threadIdx.x;  // 64
  float a0 = 0.f, a1 = 0.f;
  for (int k = lane; k < 256; k += 64) {
    float qv = qstar[(size_t)g * 256 + k];
    a0 += qv * WL[k];
    a1 += qv * WL[256 + k];
  }
#pragma unroll
  for (int sh = 32; sh; sh >>= 1) {
    a0 += __shfl_xor(a0, sh);
    a1 += __shfl_xor(a1, sh);
  }
  if (lane == 0) {
    out[2 * g + 0] = a0 + bL[0];
    out[2 * g + 1] = a1 + bL[1];
  }
}

// ---------------- launch ----------------

extern "C" void kernel_launch(void* const* d_in, const int* in_sizes, int n_in,
                              void* d_out, int out_size, void* d_ws, size_t ws_size,
                              hipStream_t stream) {
  const float* x = (const float*)d_in[0];
  const int* ei = (const int*)d_in[1];
  const int* batch = (const int*)d_in[2];
  const float* gW[4]  = {(const float*)d_in[3],  (const float*)d_in[7],
                         (const float*)d_in[11], (const float*)d_in[15]};
  const float* gb[4]  = {(const float*)d_in[4],  (const float*)d_in[8],
                         (const float*)d_in[12], (const float*)d_in[16]};
  const float* gga[4] = {(const float*)d_in[5],  (const float*)d_in[9],
                         (const float*)d_in[13], (const float*)d_in[17]};
  const float* gbe[4] = {(const float*)d_in[6],  (const float*)d_in[10],
                         (const float*)d_in[14], (const float*)d_in[18]};
  const float* Wih0 = (const float*)d_in[19];
  const float* Whh0 = (const float*)d_in[20];
  const float* b0   = (const float*)d_in[21];
  const float* WihR = (const float*)d_in[22];
  const float* WhhR = (const float*)d_in[23];
  const float* bR   = (const float*)d_in[24];
  const float* linW = (const float*)d_in[25];
  const float* linb = (const float*)d_in[26];
  float* out = (float*)d_out;

  char* base = (char*)d_ws;
  size_t off = 0;
  auto allocf = [&](size_t n) { float* p = (float*)(base + off); off += n * sizeof(float); return p; };
  float* xa    = allocf(6400000);
  float* xb    = allocf(6400000);
  float* ginWT = allocf(65536);    // 4 x [128][128] k-major
  float* WT0   = allocf(196608);   // [384][512]
  float* WTR   = allocf(393216);   // 3 x [256][512]
  float* bc0   = allocf(512);
  float* bcR   = allocf(1536);
  float* ebuf  = allocf(50000);
  // ---- zero region starts here (floats then ints, contiguous) ----
  float* stats = allocf(1024);     // 4 x (sum128|sq128)
  float* sshf  = allocf(1024);     // 4 x (scale128|shift128)
  float* cbuf  = allocf(131072);   // 4 x 256x128
  float* hbuf  = allocf(262144);   // [4][2][256x128]
  float* qstar = allocf(65536);    // 256x256
  int* deg = (int*)(base + off); off += 50000 * 4;
  int* gcount = (int*)(base + off); off += 256 * 4;
  // ---- end zero region: 460800 + 50256 = 511056 words = 127764 float4 ----
  int* row_start = (int*)(base + off); off += 50004 * 4;
  int* cursor = (int*)(base + off); off += 50000 * 4;
  int* gptr = (int*)(base + off); off += 260 * 4;
  int* csr = (int*)(base + off); off += 800000 * 4;
  int* bsum = (int*)(base + off); off += 256 * 4;
  int* boff = (int*)(base + off); off += 256 * 4;
  (void)ws_size; (void)in_sizes; (void)n_in; (void)out_size;

  // prep
  zero4_kernel<<<500, 256, 0, stream>>>((float4*)stats, 127764);
  combined_hist_kernel<<<3321, 256, 0, stream>>>(ei, batch, deg, gcount);
  chunk_sum_kernel<<<196, 256, 0, stream>>>(deg, bsum, NN);
  scan_bsum_kernel<<<1, 256, 0, stream>>>(bsum, boff, 196);
  chunk_scan_kernel<<<196, 256, 0, stream>>>(deg, boff, row_start, cursor, NN);
  scan256_kernel<<<1, 256, 0, stream>>>(gcount, gptr);
  scatter_kernel<<<3125, 256, 0, stream>>>(ei, cursor, csr);
  prep_weights_kernel<<<2568, 256, 0, stream>>>(gW[0], gW[1], gW[2], gW[3], Wih0, Whh0,
                                                WihR, WhhR, b0, bR, ginWT, WT0, WTR, bc0, bcR);

  // GIN layer 1
  gin_agg_kernel<<<12500, 256, 0, stream>>>(x, row_start, csr, nullptr, nullptr, xb);
  gemm_gin_kernel<<<1564, 256, 0, stream>>>(xb, ginWT + 0 * 16384, gb[0], nullptr, nullptr,
                                            xa, stats + 0, stats + 128, NN);
  bn_finalize_kernel<<<1, 128, 0, stream>>>(stats + 0, stats + 128, gga[0], gbe[0], sshf + 0, sshf + 128);
  gemm_gin_kernel<<<1564, 256, 0, stream>>>(xa, ginWT + 1 * 16384, gb[1], sshf + 0, sshf + 128,
                                            xb, stats + 256, stats + 384, NN);
  bn_finalize_kernel<<<1, 128, 0, stream>>>(stats + 256, stats + 384, gga[1], gbe[1], sshf + 256, sshf + 384);
  // GIN layer 2 (BN2's affine+relu fused into the gather)
  gin_agg_kernel<<<12500, 256, 0, stream>>>(xb, row_start, csr, sshf + 256, sshf + 384, xa);
  gemm_gin_kernel<<<1564, 256, 0, stream>>>(xa, ginWT + 2 * 16384, gb[2], nullptr, nullptr,
                                            xb, stats + 512, stats + 640, NN);
  bn_finalize_kernel<<<1, 128, 0, stream>>>(stats + 512, stats + 640, gga[2], gbe[2], sshf + 512, sshf + 640);
  gemm_gin_kernel<<<1564, 256, 0, stream>>>(xb, ginWT + 3 * 16384, gb[3], sshf + 512, sshf + 640,
                                            xa, stats + 768, stats + 896, NN);
  bn_finalize_kernel<<<1, 128, 0, stream>>>(stats + 768, stats + 896, gga[3], gbe[3], sshf + 768, sshf + 896);
  affine_relu_kernel<<<6250, 256, 0, stream>>>(xa, sshf + 768, sshf + 896);
  // final node features in xa

  // Set2Set
  dim3 lg(8, 16);
  for (int step = 0; step < 4; ++step) {
    int p = step & 1, pq = 1 - p;
    float* h0r = hbuf + (size_t)(0 * 2 + p) * 32768;  float* h0w = hbuf + (size_t)(0 * 2 + pq) * 32768;
    float* h1r = hbuf + (size_t)(1 * 2 + p) * 32768;  float* h1w = hbuf + (size_t)(1 * 2 + pq) * 32768;
    float* h2r = hbuf + (size_t)(2 * 2 + p) * 32768;  float* h2w = hbuf + (size_t)(2 * 2 + pq) * 32768;
    float* h3r = hbuf + (size_t)(3 * 2 + p) * 32768;  float* h3w = hbuf + (size_t)(3 * 2 + pq) * 32768;
    lstm_cell_kernel<<<lg, 256, 0, stream>>>(qstar, 256, 256, h0r, WT0, bc0, cbuf + 0, h0w, 384);
    lstm_cell_kernel<<<lg, 256, 0, stream>>>(h0w, 128, 128, h1r, WTR + 0, bcR + 0, cbuf + 32768, h1w, 256);
    lstm_cell_kernel<<<lg, 256, 0, stream>>>(h1w, 128, 128, h2r, WTR + 131072, bcR + 512, cbuf + 65536, h2w, 256);
    lstm_cell_kernel<<<lg, 256, 0, stream>>>(h2w, 128, 128, h3r, WTR + 262144, bcR + 1024, cbuf + 98304, h3w, 256);
    attention_kernel<<<256, 256, 0, stream>>>(xa, gptr, h3w, ebuf, qstar);
  }
  final_linear_kernel<<<256, 64, 0, stream>>>(qstar, linW, linb, out);
}

// Round 3
// 811.921 us; speedup vs baseline: 1.2851x; 1.1692x over previous
//
#include <hip/hip_runtime.h>
#include <math.h>

#define NN 50000
#define EE 800000
#define BBG 256
#define HHC 128
#define SEG_CAP 240
#define NBIN 196   // coarse bins of 256 nodes
#define NBLK 196   // blocks in K1/K3 (4096 edges each)

// ---------------- utility ----------------

__global__ void zero4_kernel(float4* p, int n) {
  int i = blockIdx.x * 256 + threadIdx.x;
  if (i < n) p[i] = make_float4(0.f, 0.f, 0.f, 0.f);
}

// batch is sorted: gptr[g] = first index with batch >= g; gptr[256] = NN
__global__ void gptr_boundary_kernel(const int* __restrict__ batch, int* __restrict__ gptr) {
  int i = blockIdx.x * 256 + threadIdx.x;
  if (i >= NN) return;
  int b = batch[i];
  int prev = (i == 0) ? -1 : batch[i - 1];
  for (int g = prev + 1; g <= b; ++g) gptr[g] = i;
  if (i == NN - 1) {
    for (int g = b + 1; g <= BBG; ++g) gptr[g] = NN;
  }
}

// ---- atomic-free CSR build (two-level counting sort) ----

// K1: per-block LDS histogram over coarse bins -> partial[bin][block]
__global__ __launch_bounds__(256) void coarse_hist_kernel(const int* __restrict__ ei,
                                                          int* __restrict__ partial) {
  __shared__ int hist[NBIN];
  int tid = threadIdx.x, b = blockIdx.x;
  if (tid < NBIN) hist[tid] = 0;
  __syncthreads();
  const int4* dst4 = (const int4*)(ei + EE);
#pragma unroll
  for (int c = 0; c < 4; ++c) {
    int idx = b * 1024 + c * 256 + tid;
    if (idx < EE / 4) {
      int4 d = dst4[idx];
      atomicAdd(&hist[d.x >> 8], 1);
      atomicAdd(&hist[d.y >> 8], 1);
      atomicAdd(&hist[d.z >> 8], 1);
      atomicAdd(&hist[d.w >> 8], 1);
    }
  }
  __syncthreads();
  if (tid < NBIN) partial[tid * NBLK + b] = hist[tid];
}

// K2a: per-bin scan across blocks -> block_base (local excl), total[bin]
__global__ void scan_partials_kernel(const int* __restrict__ partial,
                                     int* __restrict__ block_base, int* __restrict__ total) {
  __shared__ int buf[256];
  int bin = blockIdx.x, tid = threadIdx.x;
  int v = (tid < NBLK) ? partial[bin * NBLK + tid] : 0;
  buf[tid] = v;
  __syncthreads();
  for (int off = 1; off < 256; off <<= 1) {
    int t = (tid >= off) ? buf[tid - off] : 0;
    __syncthreads();
    buf[tid] += t;
    __syncthreads();
  }
  if (tid < NBLK) block_base[bin * NBLK + tid] = buf[tid] - v;
  if (tid == 255) total[bin] = buf[255];
}

// K2b: scan totals -> coarse_base[0..NBIN]
__global__ void scan_totals_kernel(const int* __restrict__ total, int* __restrict__ coarse_base) {
  __shared__ int buf[256];
  int tid = threadIdx.x;
  int v = (tid < NBIN) ? total[tid] : 0;
  buf[tid] = v;
  __syncthreads();
  for (int off = 1; off < 256; off <<= 1) {
    int t = (tid >= off) ? buf[tid - off] : 0;
    __syncthreads();
    buf[tid] += t;
    __syncthreads();
  }
  if (tid < NBIN) coarse_base[tid] = buf[tid] - v;
  if (tid == 255) coarse_base[NBIN] = buf[255];
}

// K3: scatter packed (src<<8 | dst&255) into coarse buckets, LDS cursors only
__global__ __launch_bounds__(256) void bucket_scatter_kernel(const int* __restrict__ ei,
                                                             const int* __restrict__ coarse_base,
                                                             const int* __restrict__ block_base,
                                                             int* __restrict__ packed) {
  __shared__ int cursor[NBIN];
  int tid = threadIdx.x, b = blockIdx.x;
  if (tid < NBIN) cursor[tid] = coarse_base[tid] + block_base[tid * NBLK + b];
  __syncthreads();
  const int4* src4 = (const int4*)ei;
  const int4* dst4 = (const int4*)(ei + EE);
#pragma unroll
  for (int c = 0; c < 4; ++c) {
    int idx = b * 1024 + c * 256 + tid;
    if (idx < EE / 4) {
      int4 s = src4[idx];
      int4 d = dst4[idx];
      int p;
      p = atomicAdd(&cursor[d.x >> 8], 1); packed[p] = (s.x << 8) | (d.x & 255);
      p = atomicAdd(&cursor[d.y >> 8], 1); packed[p] = (s.y << 8) | (d.y & 255);
      p = atomicAdd(&cursor[d.z >> 8], 1); packed[p] = (s.z << 8) | (d.z & 255);
      p = atomicAdd(&cursor[d.w >> 8], 1); packed[p] = (s.w << 8) | (d.w & 255);
    }
  }
}

// K4: per-bucket fine histogram + scan -> row_start + final csr
__global__ __launch_bounds__(256) void csr_finalize_kernel(const int* __restrict__ packed,
                                                           const int* __restrict__ coarse_base,
                                                           int* __restrict__ row_start,
                                                           int* __restrict__ csr) {
  __shared__ int fh[256];
  __shared__ int fb[256];
  int bin = blockIdx.x, tid = threadIdx.x;
  int e0 = coarse_base[bin], e1 = coarse_base[bin + 1];
  fh[tid] = 0;
  __syncthreads();
  for (int e = e0 + tid; e < e1; e += 256) atomicAdd(&fh[packed[e] & 255], 1);
  __syncthreads();
  int v = fh[tid];
  fb[tid] = v;
  __syncthreads();
  for (int off = 1; off < 256; off <<= 1) {
    int t = (tid >= off) ? fb[tid - off] : 0;
    __syncthreads();
    fb[tid] += t;
    __syncthreads();
  }
  int excl = fb[tid] - v;
  int node = bin * 256 + tid;
  if (node < NN) row_start[node] = e0 + excl;
  if (bin == NBIN - 1 && tid == 0) row_start[NN] = EE;
  __syncthreads();
  fb[tid] = excl;  // cursor
  __syncthreads();
  for (int e = e0 + tid; e < e1; e += 256) {
    int p = packed[e];
    int pos = atomicAdd(&fb[p & 255], 1);
    csr[e0 + pos] = p >> 8;
  }
}

// ---------------- weight prep (single kernel) ----------------
__global__ void prep_weights_kernel(const float* __restrict__ W0, const float* __restrict__ W1,
                                    const float* __restrict__ W2, const float* __restrict__ W3,
                                    const float* __restrict__ Wih0, const float* __restrict__ Whh0,
                                    const float* __restrict__ WihR, const float* __restrict__ WhhR,
                                    const float* __restrict__ b0, const float* __restrict__ bR,
                                    float* __restrict__ ginWT, float* __restrict__ WT0,
                                    float* __restrict__ WTR, float* __restrict__ bc0,
                                    float* __restrict__ bcR) {
  int idx = blockIdx.x * 256 + threadIdx.x;  // grid 2568*256 = 657408 exact
  if (idx < 65536) {
    int m = idx >> 14;
    int r = idx & 16383;
    int k = r >> 7, o = r & 127;
    const float* W = (m == 0) ? W0 : (m == 1) ? W1 : (m == 2) ? W2 : W3;
    ginWT[idx] = W[o * 128 + k];
  } else if (idx < 262144) {
    int t = idx - 65536;
    int k = t >> 9, op = t & 511;
    int j = op >> 2, g = op & 3;
    int row = g * 128 + j;
    WT0[t] = (k < 256) ? Wih0[row * 256 + k] : Whh0[row * 128 + (k - 256)];
  } else if (idx < 655360) {
    int t = idx - 262144;
    int l = t >> 17;
    int rem = t & 131071;
    int k = rem >> 9, op = rem & 511;
    int j = op >> 2, g = op & 3;
    int row = g * 128 + j;
    WTR[t] = (k < 128) ? WihR[((size_t)l * 512 + row) * 128 + k]
                       : WhhR[((size_t)l * 512 + row) * 128 + (k - 128)];
  } else {
    int t = idx - 655360;
    if (t < 512) {
      bc0[t] = b0[(t & 3) * 128 + (t >> 2)];
    } else {
      int u = t - 512;
      int l = u >> 9, op = u & 511;
      bcR[u] = bR[l * 512 + (op & 3) * 128 + (op >> 2)];
    }
  }
}

// ---------------- GIN ----------------

// one wave per node: out[i] = f(x[i]) + sum_{j in CSR(i)} f(x[j])
__global__ void gin_agg_kernel(const float* __restrict__ xin, const int* __restrict__ row_start,
                               const int* __restrict__ csr,
                               const float* __restrict__ pre_scale,
                               const float* __restrict__ pre_shift,
                               float* __restrict__ outp) {
  int node = blockIdx.x * 4 + (threadIdx.x >> 6);  // exact: 12500*4 = 50000
  int lane = threadIdx.x & 63;
  const float2* x2 = (const float2*)xin;
  int s0 = row_start[node], s1 = row_start[node + 1];
  float2 acc;
  if (pre_scale) {
    float sc0 = pre_scale[2 * lane], sc1 = pre_scale[2 * lane + 1];
    float sh0 = pre_shift[2 * lane], sh1 = pre_shift[2 * lane + 1];
    float2 s = x2[(size_t)node * 64 + lane];
    acc.x = fmaxf(fmaf(s.x, sc0, sh0), 0.f);
    acc.y = fmaxf(fmaf(s.y, sc1, sh1), 0.f);
    for (int j = s0; j < s1; ++j) {
      float2 v = x2[(size_t)csr[j] * 64 + lane];
      acc.x += fmaxf(fmaf(v.x, sc0, sh0), 0.f);
      acc.y += fmaxf(fmaf(v.y, sc1, sh1), 0.f);
    }
  } else {
    acc = x2[(size_t)node * 64 + lane];
    for (int j = s0; j < s1; ++j) {
      float2 v = x2[(size_t)csr[j] * 64 + lane];
      acc.x += v.x;
      acc.y += v.y;
    }
  }
  ((float2*)outp)[(size_t)node * 64 + lane] = acc;
}

// C = f(A) @ W^T + b, with per-channel sum/sumsq atomics for BN.
__global__ __launch_bounds__(256) void gemm_gin_kernel(
    const float* __restrict__ A, const float* __restrict__ WT,
    const float* __restrict__ bias,
    const float* __restrict__ pre_scale, const float* __restrict__ pre_shift,
    float* __restrict__ C,
    float* __restrict__ ssum, float* __restrict__ ssq, int M) {
  __shared__ float As[64][132];
  __shared__ float Wt[128][68];
  int tid = threadIdx.x;
  int tx = tid & 15, ty = tid >> 4;
  int bx = blockIdx.x & 1, by = blockIdx.x >> 1;
  int row0 = by * 64, c0 = bx * 64;
#pragma unroll
  for (int i = 0; i < 8; ++i) {
    int slot = tid + i * 256;
    int r = slot >> 5, k4 = (slot & 31) << 2;
    float4 v = make_float4(0.f, 0.f, 0.f, 0.f);
    if (row0 + r < M) v = *(const float4*)(A + (size_t)(row0 + r) * 128 + k4);
    if (pre_scale) {
      v.x = fmaxf(fmaf(v.x, pre_scale[k4 + 0], pre_shift[k4 + 0]), 0.f);
      v.y = fmaxf(fmaf(v.y, pre_scale[k4 + 1], pre_shift[k4 + 1]), 0.f);
      v.z = fmaxf(fmaf(v.z, pre_scale[k4 + 2], pre_shift[k4 + 2]), 0.f);
      v.w = fmaxf(fmaf(v.w, pre_scale[k4 + 3], pre_shift[k4 + 3]), 0.f);
    }
    *(float4*)&As[r][k4] = v;
  }
#pragma unroll
  for (int i = 0; i < 8; ++i) {
    int slot = tid + i * 256;
    int k = slot >> 4, c4 = (slot & 15) << 2;
    *(float4*)&Wt[k][c4] = *(const float4*)(WT + (size_t)k * 128 + c0 + c4);
  }
  __syncthreads();
  float acc[4][4];
#pragma unroll
  for (int i = 0; i < 4; ++i)
#pragma unroll
    for (int j = 0; j < 4; ++j) acc[i][j] = 0.f;
#pragma unroll 4
  for (int kk = 0; kk < 128; kk += 4) {
    float4 w0 = *(const float4*)&Wt[kk + 0][tx << 2];
    float4 w1 = *(const float4*)&Wt[kk + 1][tx << 2];
    float4 w2 = *(const float4*)&Wt[kk + 2][tx << 2];
    float4 w3 = *(const float4*)&Wt[kk + 3][tx << 2];
#pragma unroll
    for (int i = 0; i < 4; ++i) {
      float4 a = *(const float4*)&As[(ty << 2) + i][kk];
      acc[i][0] += a.x * w0.x + a.y * w1.x + a.z * w2.x + a.w * w3.x;
      acc[i][1] += a.x * w0.y + a.y * w1.y + a.z * w2.y + a.w * w3.y;
      acc[i][2] += a.x * w0.z + a.y * w1.z + a.z * w2.z + a.w * w3.z;
      acc[i][3] += a.x * w0.w + a.y * w1.w + a.z * w2.w + a.w * w3.w;
    }
  }
  __syncthreads();
  float b0v = bias[c0 + (tx << 2) + 0];
  float b1v = bias[c0 + (tx << 2) + 1];
  float b2v = bias[c0 + (tx << 2) + 2];
  float b3v = bias[c0 + (tx << 2) + 3];
  float psum[4] = {0.f, 0.f, 0.f, 0.f}, psq[4] = {0.f, 0.f, 0.f, 0.f};
#pragma unroll
  for (int i = 0; i < 4; ++i) {
    int r = row0 + (ty << 2) + i;
    if (r < M) {
      float4 v;
      v.x = acc[i][0] + b0v; v.y = acc[i][1] + b1v;
      v.z = acc[i][2] + b2v; v.w = acc[i][3] + b3v;
      *(float4*)(C + (size_t)r * 128 + c0 + (tx << 2)) = v;
      psum[0] += v.x; psum[1] += v.y; psum[2] += v.z; psum[3] += v.w;
      psq[0] += v.x * v.x; psq[1] += v.y * v.y; psq[2] += v.z * v.z; psq[3] += v.w * v.w;
    }
  }
  float* red = &As[0][0];
#pragma unroll
  for (int j = 0; j < 4; ++j) {
    red[ty * 68 + (tx << 2) + j] = psum[j];
    red[1088 + ty * 68 + (tx << 2) + j] = psq[j];
  }
  __syncthreads();
  if (tid < 64) {
    float s = 0.f, sq = 0.f;
#pragma unroll
    for (int t = 0; t < 16; ++t) { s += red[t * 68 + tid]; sq += red[1088 + t * 68 + tid]; }
    atomicAdd(&ssum[c0 + tid], s);
    atomicAdd(&ssq[c0 + tid], sq);
  }
}

__global__ void bn_finalize_kernel(const float* __restrict__ sums, const float* __restrict__ sqs,
                                   const float* __restrict__ gamma, const float* __restrict__ beta,
                                   float* __restrict__ scale, float* __restrict__ shift) {
  int c = threadIdx.x;  // 128
  const float invN = 1.0f / (float)NN;
  float m = sums[c] * invN;
  float v = sqs[c] * invN - m * m;
  float rs = rsqrtf(v + 1e-5f);
  float sc = gamma[c] * rs;
  scale[c] = sc;
  shift[c] = beta[c] - m * sc;
}

// ---------------- Set2Set ----------------

__global__ __launch_bounds__(256) void lstm_cell_kernel(
    const float* __restrict__ inA, int pitchA, int splitK,
    const float* __restrict__ inB,
    const float* __restrict__ WT, const float* __restrict__ bias,
    float* __restrict__ cstate, float* __restrict__ hout, int K) {
  __shared__ float As[16][132];
  __shared__ float Wt[128][68];
  int tid = threadIdx.x;
  int tx = tid & 15, ty = tid >> 4;
  int bx = blockIdx.x, by = blockIdx.y;
  int row0 = by * 16, c0 = bx * 64;
  float acc[4] = {0.f, 0.f, 0.f, 0.f};
  for (int kc = 0; kc < K; kc += 128) {
#pragma unroll
    for (int i = 0; i < 2; ++i) {
      int slot = tid + i * 256;
      int r = slot >> 5, k4 = (slot & 31) << 2;
      int gc = kc + k4;
      const float* src = (gc < splitK) ? inA + (size_t)(row0 + r) * pitchA + gc
                                       : inB + (size_t)(row0 + r) * 128 + (gc - splitK);
      *(float4*)&As[r][k4] = *(const float4*)src;
    }
#pragma unroll
    for (int i = 0; i < 8; ++i) {
      int slot = tid + i * 256;
      int k = slot >> 4, c4 = (slot & 15) << 2;
      *(float4*)&Wt[k][c4] = *(const float4*)(WT + (size_t)(kc + k) * 512 + c0 + c4);
    }
    __syncthreads();
#pragma unroll 4
    for (int kk = 0; kk < 128; kk += 4) {
      float4 a = *(const float4*)&As[ty][kk];
      float4 w0 = *(const float4*)&Wt[kk + 0][tx << 2];
      float4 w1 = *(const float4*)&Wt[kk + 1][tx << 2];
      float4 w2 = *(const float4*)&Wt[kk + 2][tx << 2];
      float4 w3 = *(const float4*)&Wt[kk + 3][tx << 2];
      acc[0] += a.x * w0.x + a.y * w1.x + a.z * w2.x + a.w * w3.x;
      acc[1] += a.x * w0.y + a.y * w1.y + a.z * w2.y + a.w * w3.y;
      acc[2] += a.x * w0.z + a.y * w1.z + a.z * w2.z + a.w * w3.z;
      acc[3] += a.x * w0.w + a.y * w1.w + a.z * w2.w + a.w * w3.w;
    }
    __syncthreads();
  }
  int b = row0 + ty;
  int j = bx * 16 + tx;
  int ob = c0 + (tx << 2);
  float ii = acc[0] + bias[ob + 0];
  float ff = acc[1] + bias[ob + 1];
  float gg = acc[2] + bias[ob + 2];
  float oo = acc[3] + bias[ob + 3];
  float cp = cstate[b * 128 + j];
  float si = 1.f / (1.f + expf(-ii));
  float sf = 1.f / (1.f + expf(-ff));
  float so = 1.f / (1.f + expf(-oo));
  float cn = sf * cp + si * tanhf(gg);
  float hv = so * tanhf(cn);
  cstate[b * 128 + j] = cn;
  hout[b * 128 + j] = hv;
}

// per-graph segment softmax attention with fused BN affine+relu on x reads.
__global__ __launch_bounds__(256) void attention_kernel(
    const float* __restrict__ x, const int* __restrict__ gptr,
    const float* __restrict__ h3,
    const float* __restrict__ pre_scale, const float* __restrict__ pre_shift,
    float* __restrict__ ebuf, float* __restrict__ qstar) {
  int g = blockIdx.x;
  int tid = threadIdx.x;
  int lane = tid & 63, w = tid >> 6;
  __shared__ float xs[SEG_CAP * 128];
  __shared__ float es[SEG_CAP];
  __shared__ float q[128];
  __shared__ float wred[4];
  __shared__ float rpart[4][128];
  __shared__ float sm, ssv;
  if (tid < 128) q[tid] = h3[g * 128 + tid];
  __syncthreads();
  int s0 = gptr[g], s1 = gptr[g + 1];
  bool fit = (s1 - s0) <= SEG_CAP;
  const float2* x2 = (const float2*)x;
  float2 qv = ((const float2*)q)[lane];
  float sc0 = pre_scale[2 * lane], sc1 = pre_scale[2 * lane + 1];
  float sh0 = pre_shift[2 * lane], sh1 = pre_shift[2 * lane + 1];
  // pass 1: e + max (stage transformed x into LDS)
  float wmax = -3.0e38f;
  for (int n = s0 + w; n < s1; n += 4) {
    float2 v = x2[(size_t)n * 64 + lane];
    v.x = fmaxf(fmaf(v.x, sc0, sh0), 0.f);
    v.y = fmaxf(fmaf(v.y, sc1, sh1), 0.f);
    if (fit) {
      xs[(n - s0) * 128 + 2 * lane] = v.x;
      xs[(n - s0) * 128 + 2 * lane + 1] = v.y;
    }
    float e = v.x * qv.x + v.y * qv.y;
#pragma unroll
    for (int sh = 32; sh; sh >>= 1) e += __shfl_xor(e, sh);
    if (lane == 0) { if (fit) es[n - s0] = e; else ebuf[n] = e; }
    wmax = fmaxf(wmax, e);
  }
  if (lane == 0) wred[w] = wmax;
  __syncthreads();
  if (tid == 0) sm = fmaxf(fmaxf(wred[0], wred[1]), fmaxf(wred[2], wred[3]));
  __syncthreads();
  float m = sm;
  // pass 2: sum exp
  float loc = 0.f;
  for (int n = s0 + tid; n < s1; n += 256) {
    float e = fit ? es[n - s0] : ebuf[n];
    loc += expf(e - m);
  }
#pragma unroll
  for (int sh = 32; sh; sh >>= 1) loc += __shfl_xor(loc, sh);
  __syncthreads();
  if (lane == 0) wred[w] = loc;
  __syncthreads();
  if (tid == 0) ssv = wred[0] + wred[1] + wred[2] + wred[3];
  __syncthreads();
  float inv = 1.0f / ssv;
  // pass 3: r = sum a*x
  float rx = 0.f, ry = 0.f;
  for (int n = s0 + w; n < s1; n += 4) {
    float e = fit ? es[n - s0] : ebuf[n];
    float coef = expf(e - m) * inv;
    float vx, vy;
    if (fit) {
      vx = xs[(n - s0) * 128 + 2 * lane];
      vy = xs[(n - s0) * 128 + 2 * lane + 1];
    } else {
      float2 v = x2[(size_t)n * 64 + lane];
      vx = fmaxf(fmaf(v.x, sc0, sh0), 0.f);
      vy = fmaxf(fmaf(v.y, sc1, sh1), 0.f);
    }
    rx += coef * vx; ry += coef * vy;
  }
  rpart[w][2 * lane] = rx;
  rpart[w][2 * lane + 1] = ry;
  __syncthreads();
  if (tid < 128) {
    float r = rpart[0][tid] + rpart[1][tid] + rpart[2][tid] + rpart[3][tid];
    qstar[(size_t)g * 256 + tid] = q[tid];
    qstar[(size_t)g * 256 + 128 + tid] = r;
  }
}

__global__ void final_linear_kernel(const float* __restrict__ qstar, const float* __restrict__ WL,
                                    const float* __restrict__ bL, float* __restrict__ out) {
  int g = blockIdx.x;
  int lane = threadIdx.x;  // 64
  float a0 = 0.f, a1 = 0.f;
  for (int k = lane; k < 256; k += 64) {
    float qv = qstar[(size_t)g * 256 + k];
    a0 += qv * WL[k];
    a1 += qv * WL[256 + k];
  }
#pragma unroll
  for (int sh = 32; sh; sh >>= 1) {
    a0 += __shfl_xor(a0, sh);
    a1 += __shfl_xor(a1, sh);
  }
  if (lane == 0) {
    out[2 * g + 0] = a0 + bL[0];
    out[2 * g + 1] = a1 + bL[1];
  }
}

// ---------------- launch ----------------

extern "C" void kernel_launch(void* const* d_in, const int* in_sizes, int n_in,
                              void* d_out, int out_size, void* d_ws, size_t ws_size,
                              hipStream_t stream) {
  const float* x = (const float*)d_in[0];
  const int* ei = (const int*)d_in[1];
  const int* batch = (const int*)d_in[2];
  const float* gW[4]  = {(const float*)d_in[3],  (const float*)d_in[7],
                         (const float*)d_in[11], (const float*)d_in[15]};
  const float* gb[4]  = {(const float*)d_in[4],  (const float*)d_in[8],
                         (const float*)d_in[12], (const float*)d_in[16]};
  const float* gga[4] = {(const float*)d_in[5],  (const float*)d_in[9],
                         (const float*)d_in[13], (const float*)d_in[17]};
  const float* gbe[4] = {(const float*)d_in[6],  (const float*)d_in[10],
                         (const float*)d_in[14], (const float*)d_in[18]};
  const float* Wih0 = (const float*)d_in[19];
  const float* Whh0 = (const float*)d_in[20];
  const float* b0   = (const float*)d_in[21];
  const float* WihR = (const float*)d_in[22];
  const float* WhhR = (const float*)d_in[23];
  const float* bR   = (const float*)d_in[24];
  const float* linW = (const float*)d_in[25];
  const float* linb = (const float*)d_in[26];
  float* out = (float*)d_out;

  char* base = (char*)d_ws;
  size_t off = 0;
  auto allocf = [&](size_t n) { float* p = (float*)(base + off); off += n * sizeof(float); return p; };
  float* xa    = allocf(6400000);
  float* xb    = allocf(6400000);
  float* ginWT = allocf(65536);
  float* WT0   = allocf(196608);
  float* WTR   = allocf(393216);
  float* bc0   = allocf(512);
  float* bcR   = allocf(1536);
  float* ebuf  = allocf(50000);
  // ---- zero region (contiguous): 460800 floats = 115200 float4 ----
  float* stats = allocf(1024);
  float* sshf  = allocf(1024);
  float* cbuf  = allocf(131072);
  float* hbuf  = allocf(262144);
  float* qstar = allocf(65536);
  // ---- ints (all fully written before read; no zeroing needed) ----
  int* row_start = (int*)(base + off); off += 50004 * 4;
  int* gptr = (int*)(base + off); off += 260 * 4;
  int* csr = (int*)(base + off); off += 800000 * 4;
  int* packed = (int*)(base + off); off += 800000 * 4;
  int* partial = (int*)(base + off); off += NBIN * NBLK * 4;
  int* block_base = (int*)(base + off); off += NBIN * NBLK * 4;
  int* total = (int*)(base + off); off += 256 * 4;
  int* coarse_base = (int*)(base + off); off += 260 * 4;
  (void)ws_size; (void)in_sizes; (void)n_in; (void)out_size;

  // prep
  zero4_kernel<<<450, 256, 0, stream>>>((float4*)stats, 115200);
  gptr_boundary_kernel<<<196, 256, 0, stream>>>(batch, gptr);
  coarse_hist_kernel<<<NBLK, 256, 0, stream>>>(ei, partial);
  scan_partials_kernel<<<NBIN, 256, 0, stream>>>(partial, block_base, total);
  scan_totals_kernel<<<1, 256, 0, stream>>>(total, coarse_base);
  bucket_scatter_kernel<<<NBLK, 256, 0, stream>>>(ei, coarse_base, block_base, packed);
  csr_finalize_kernel<<<NBIN, 256, 0, stream>>>(packed, coarse_base, row_start, csr);
  prep_weights_kernel<<<2568, 256, 0, stream>>>(gW[0], gW[1], gW[2], gW[3], Wih0, Whh0,
                                                WihR, WhhR, b0, bR, ginWT, WT0, WTR, bc0, bcR);

  // GIN layer 1
  gin_agg_kernel<<<12500, 256, 0, stream>>>(x, row_start, csr, nullptr, nullptr, xb);
  gemm_gin_kernel<<<1564, 256, 0, stream>>>(xb, ginWT + 0 * 16384, gb[0], nullptr, nullptr,
                                            xa, stats + 0, stats + 128, NN);
  bn_finalize_kernel<<<1, 128, 0, stream>>>(stats + 0, stats + 128, gga[0], gbe[0], sshf + 0, sshf + 128);
  gemm_gin_kernel<<<1564, 256, 0, stream>>>(xa, ginWT + 1 * 16384, gb[1], sshf + 0, sshf + 128,
                                            xb, stats + 256, stats + 384, NN);
  bn_finalize_kernel<<<1, 128, 0, stream>>>(stats + 256, stats + 384, gga[1], gbe[1], sshf + 256, sshf + 384);
  // GIN layer 2 (BN2 fused into the gather)
  gin_agg_kernel<<<12500, 256, 0, stream>>>(xb, row_start, csr, sshf + 256, sshf + 384, xa);
  gemm_gin_kernel<<<1564, 256, 0, stream>>>(xa, ginWT + 2 * 16384, gb[2], nullptr, nullptr,
                                            xb, stats + 512, stats + 640, NN);
  bn_finalize_kernel<<<1, 128, 0, stream>>>(stats + 512, stats + 640, gga[2], gbe[2], sshf + 512, sshf + 640);
  gemm_gin_kernel<<<1564, 256, 0, stream>>>(xb, ginWT + 3 * 16384, gb[3], sshf + 512, sshf + 640,
                                            xa, stats + 768, stats + 896, NN);
  bn_finalize_kernel<<<1, 128, 0, stream>>>(stats + 768, stats + 896, gga[3], gbe[3], sshf + 768, sshf + 896);
  // xa holds pre-BN4 features; BN4 affine+relu fused into attention reads

  // Set2Set
  dim3 lg(8, 16);
  for (int step = 0; step < 4; ++step) {
    int p = step & 1, pq = 1 - p;
    float* h0r = hbuf + (size_t)(0 * 2 + p) * 32768;  float* h0w = hbuf + (size_t)(0 * 2 + pq) * 32768;
    float* h1r = hbuf + (size_t)(1 * 2 + p) * 32768;  float* h1w = hbuf + (size_t)(1 * 2 + pq) * 32768;
    float* h2r = hbuf + (size_t)(2 * 2 + p) * 32768;  float* h2w = hbuf + (size_t)(2 * 2 + pq) * 32768;
    float* h3r = hbuf + (size_t)(3 * 2 + p) * 32768;  float* h3w = hbuf + (size_t)(3 * 2 + pq) * 32768;
    lstm_cell_kernel<<<lg, 256, 0, stream>>>(qstar, 256, 256, h0r, WT0, bc0, cbuf + 0, h0w, 384);
    lstm_cell_kernel<<<lg, 256, 0, stream>>>(h0w, 128, 128, h1r, WTR + 0, bcR + 0, cbuf + 32768, h1w, 256);
    lstm_cell_kernel<<<lg, 256, 0, stream>>>(h1w, 128, 128, h2r, WTR + 131072, bcR + 512, cbuf + 65536, h2w, 256);
    lstm_cell_kernel<<<lg, 256, 0, stream>>>(h2w, 128, 128, h3r, WTR + 262144, bcR + 1024, cbuf + 98304, h3w, 256);
    attention_kernel<<<256, 256, 0, stream>>>(xa, gptr, h3w, sshf + 768, sshf + 896, ebuf, qstar);
  }
  final_linear_kernel<<<256, 64, 0, stream>>>(qstar, linW, linb, out);
}

// Round 4
// 752.323 us; speedup vs baseline: 1.3869x; 1.0792x over previous
//
#include <hip/hip_runtime.h>
#include <math.h>

#define NN 50000
#define EE 800000
#define BBG 256
#define HHC 128
#define SEG_CAP 240
#define NBIN 196   // coarse bins of 256 nodes
#define NBLK 196   // blocks in K1/K3 (4096 edges each)

// ---------------- utility ----------------

__global__ void zero4_kernel(float4* p, int n) {
  int i = blockIdx.x * 256 + threadIdx.x;
  if (i < n) p[i] = make_float4(0.f, 0.f, 0.f, 0.f);
}

// batch is sorted: gptr[g] = first index with batch >= g; gptr[256] = NN
__global__ void gptr_boundary_kernel(const int* __restrict__ batch, int* __restrict__ gptr) {
  int i = blockIdx.x * 256 + threadIdx.x;
  if (i >= NN) return;
  int b = batch[i];
  int prev = (i == 0) ? -1 : batch[i - 1];
  for (int g = prev + 1; g <= b; ++g) gptr[g] = i;
  if (i == NN - 1) {
    for (int g = b + 1; g <= BBG; ++g) gptr[g] = NN;
  }
}

// ---- atomic-free CSR build (two-level counting sort) ----

__global__ __launch_bounds__(256) void coarse_hist_kernel(const int* __restrict__ ei,
                                                          int* __restrict__ partial) {
  __shared__ int hist[NBIN];
  int tid = threadIdx.x, b = blockIdx.x;
  if (tid < NBIN) hist[tid] = 0;
  __syncthreads();
  const int4* dst4 = (const int4*)(ei + EE);
#pragma unroll
  for (int c = 0; c < 4; ++c) {
    int idx = b * 1024 + c * 256 + tid;
    if (idx < EE / 4) {
      int4 d = dst4[idx];
      atomicAdd(&hist[d.x >> 8], 1);
      atomicAdd(&hist[d.y >> 8], 1);
      atomicAdd(&hist[d.z >> 8], 1);
      atomicAdd(&hist[d.w >> 8], 1);
    }
  }
  __syncthreads();
  if (tid < NBIN) partial[tid * NBLK + b] = hist[tid];
}

__global__ void scan_partials_kernel(const int* __restrict__ partial,
                                     int* __restrict__ block_base, int* __restrict__ total) {
  __shared__ int buf[256];
  int bin = blockIdx.x, tid = threadIdx.x;
  int v = (tid < NBLK) ? partial[bin * NBLK + tid] : 0;
  buf[tid] = v;
  __syncthreads();
  for (int off = 1; off < 256; off <<= 1) {
    int t = (tid >= off) ? buf[tid - off] : 0;
    __syncthreads();
    buf[tid] += t;
    __syncthreads();
  }
  if (tid < NBLK) block_base[bin * NBLK + tid] = buf[tid] - v;
  if (tid == 255) total[bin] = buf[255];
}

__global__ void scan_totals_kernel(const int* __restrict__ total, int* __restrict__ coarse_base) {
  __shared__ int buf[256];
  int tid = threadIdx.x;
  int v = (tid < NBIN) ? total[tid] : 0;
  buf[tid] = v;
  __syncthreads();
  for (int off = 1; off < 256; off <<= 1) {
    int t = (tid >= off) ? buf[tid - off] : 0;
    __syncthreads();
    buf[tid] += t;
    __syncthreads();
  }
  if (tid < NBIN) coarse_base[tid] = buf[tid] - v;
  if (tid == 255) coarse_base[NBIN] = buf[255];
}

__global__ __launch_bounds__(256) void bucket_scatter_kernel(const int* __restrict__ ei,
                                                             const int* __restrict__ coarse_base,
                                                             const int* __restrict__ block_base,
                                                             int* __restrict__ packed) {
  __shared__ int cursor[NBIN];
  int tid = threadIdx.x, b = blockIdx.x;
  if (tid < NBIN) cursor[tid] = coarse_base[tid] + block_base[tid * NBLK + b];
  __syncthreads();
  const int4* src4 = (const int4*)ei;
  const int4* dst4 = (const int4*)(ei + EE);
#pragma unroll
  for (int c = 0; c < 4; ++c) {
    int idx = b * 1024 + c * 256 + tid;
    if (idx < EE / 4) {
      int4 s = src4[idx];
      int4 d = dst4[idx];
      int p;
      p = atomicAdd(&cursor[d.x >> 8], 1); packed[p] = (s.x << 8) | (d.x & 255);
      p = atomicAdd(&cursor[d.y >> 8], 1); packed[p] = (s.y << 8) | (d.y & 255);
      p = atomicAdd(&cursor[d.z >> 8], 1); packed[p] = (s.z << 8) | (d.z & 255);
      p = atomicAdd(&cursor[d.w >> 8], 1); packed[p] = (s.w << 8) | (d.w & 255);
    }
  }
}

__global__ __launch_bounds__(256) void csr_finalize_kernel(const int* __restrict__ packed,
                                                           const int* __restrict__ coarse_base,
                                                           int* __restrict__ row_start,
                                                           int* __restrict__ csr) {
  __shared__ int fh[256];
  __shared__ int fb[256];
  int bin = blockIdx.x, tid = threadIdx.x;
  int e0 = coarse_base[bin], e1 = coarse_base[bin + 1];
  fh[tid] = 0;
  __syncthreads();
  for (int e = e0 + tid; e < e1; e += 256) atomicAdd(&fh[packed[e] & 255], 1);
  __syncthreads();
  int v = fh[tid];
  fb[tid] = v;
  __syncthreads();
  for (int off = 1; off < 256; off <<= 1) {
    int t = (tid >= off) ? fb[tid - off] : 0;
    __syncthreads();
    fb[tid] += t;
    __syncthreads();
  }
  int excl = fb[tid] - v;
  int node = bin * 256 + tid;
  if (node < NN) row_start[node] = e0 + excl;
  if (bin == NBIN - 1 && tid == 0) row_start[NN] = EE;
  __syncthreads();
  fb[tid] = excl;  // cursor
  __syncthreads();
  for (int e = e0 + tid; e < e1; e += 256) {
    int p = packed[e];
    int pos = atomicAdd(&fb[p & 255], 1);
    csr[e0 + pos] = p >> 8;
  }
}

// ---------------- weight prep (single kernel) ----------------
__global__ void prep_weights_kernel(const float* __restrict__ W0, const float* __restrict__ W1,
                                    const float* __restrict__ W2, const float* __restrict__ W3,
                                    const float* __restrict__ Wih0, const float* __restrict__ Whh0,
                                    const float* __restrict__ WihR, const float* __restrict__ WhhR,
                                    const float* __restrict__ b0, const float* __restrict__ bR,
                                    float* __restrict__ ginWT, float* __restrict__ WT0,
                                    float* __restrict__ WTR, float* __restrict__ bc0,
                                    float* __restrict__ bcR) {
  int idx = blockIdx.x * 256 + threadIdx.x;  // grid 2568*256 = 657408 exact
  if (idx < 65536) {
    int m = idx >> 14;
    int r = idx & 16383;
    int k = r >> 7, o = r & 127;
    const float* W = (m == 0) ? W0 : (m == 1) ? W1 : (m == 2) ? W2 : W3;
    ginWT[idx] = W[o * 128 + k];
  } else if (idx < 262144) {
    int t = idx - 65536;
    int k = t >> 9, op = t & 511;
    int j = op >> 2, g = op & 3;
    int row = g * 128 + j;
    WT0[t] = (k < 256) ? Wih0[row * 256 + k] : Whh0[row * 128 + (k - 256)];
  } else if (idx < 655360) {
    int t = idx - 262144;
    int l = t >> 17;
    int rem = t & 131071;
    int k = rem >> 9, op = rem & 511;
    int j = op >> 2, g = op & 3;
    int row = g * 128 + j;
    WTR[t] = (k < 128) ? WihR[((size_t)l * 512 + row) * 128 + k]
                       : WhhR[((size_t)l * 512 + row) * 128 + (k - 128)];
  } else {
    int t = idx - 655360;
    if (t < 512) {
      bc0[t] = b0[(t & 3) * 128 + (t >> 2)];
    } else {
      int u = t - 512;
      int l = u >> 9, op = u & 511;
      bcR[u] = bR[l * 512 + (op & 3) * 128 + (op >> 2)];
    }
  }
}

// ---------------- GIN ----------------

// one wave per node, 8-deep pipelined gather: out[i] = f(x[i]) + sum f(x[j])
template <bool AFF>
__global__ void gin_agg_kernel(const float* __restrict__ xin, const int* __restrict__ row_start,
                               const int* __restrict__ csr,
                               const float* __restrict__ pre_scale,
                               const float* __restrict__ pre_shift,
                               float* __restrict__ outp) {
  int node = blockIdx.x * 4 + (threadIdx.x >> 6);  // exact: 12500*4 = 50000
  int lane = threadIdx.x & 63;
  const float2* x2 = (const float2*)xin;
  int s0 = row_start[node], s1 = row_start[node + 1];
  float sc0 = 0.f, sc1 = 0.f, sh0 = 0.f, sh1 = 0.f;
  if (AFF) {
    sc0 = pre_scale[2 * lane]; sc1 = pre_scale[2 * lane + 1];
    sh0 = pre_shift[2 * lane]; sh1 = pre_shift[2 * lane + 1];
  }
  float2 s = x2[(size_t)node * 64 + lane];
  float ax, ay;
  if (AFF) {
    ax = fmaxf(fmaf(s.x, sc0, sh0), 0.f);
    ay = fmaxf(fmaf(s.y, sc1, sh1), 0.f);
  } else {
    ax = s.x; ay = s.y;
  }
  float c0x = 0.f, c0y = 0.f, c1x = 0.f, c1y = 0.f;
  float c2x = 0.f, c2y = 0.f, c3x = 0.f, c3y = 0.f;
  int j = s0;
  for (; j + 8 <= s1; j += 8) {
    int i0 = csr[j + 0], i1 = csr[j + 1], i2 = csr[j + 2], i3 = csr[j + 3];
    int i4 = csr[j + 4], i5 = csr[j + 5], i6 = csr[j + 6], i7 = csr[j + 7];
    float2 v0 = x2[(size_t)i0 * 64 + lane];
    float2 v1 = x2[(size_t)i1 * 64 + lane];
    float2 v2 = x2[(size_t)i2 * 64 + lane];
    float2 v3 = x2[(size_t)i3 * 64 + lane];
    float2 v4 = x2[(size_t)i4 * 64 + lane];
    float2 v5 = x2[(size_t)i5 * 64 + lane];
    float2 v6 = x2[(size_t)i6 * 64 + lane];
    float2 v7 = x2[(size_t)i7 * 64 + lane];
    if (AFF) {
      v0.x = fmaxf(fmaf(v0.x, sc0, sh0), 0.f); v0.y = fmaxf(fmaf(v0.y, sc1, sh1), 0.f);
      v1.x = fmaxf(fmaf(v1.x, sc0, sh0), 0.f); v1.y = fmaxf(fmaf(v1.y, sc1, sh1), 0.f);
      v2.x = fmaxf(fmaf(v2.x, sc0, sh0), 0.f); v2.y = fmaxf(fmaf(v2.y, sc1, sh1), 0.f);
      v3.x = fmaxf(fmaf(v3.x, sc0, sh0), 0.f); v3.y = fmaxf(fmaf(v3.y, sc1, sh1), 0.f);
      v4.x = fmaxf(fmaf(v4.x, sc0, sh0), 0.f); v4.y = fmaxf(fmaf(v4.y, sc1, sh1), 0.f);
      v5.x = fmaxf(fmaf(v5.x, sc0, sh0), 0.f); v5.y = fmaxf(fmaf(v5.y, sc1, sh1), 0.f);
      v6.x = fmaxf(fmaf(v6.x, sc0, sh0), 0.f); v6.y = fmaxf(fmaf(v6.y, sc1, sh1), 0.f);
      v7.x = fmaxf(fmaf(v7.x, sc0, sh0), 0.f); v7.y = fmaxf(fmaf(v7.y, sc1, sh1), 0.f);
    }
    c0x += v0.x + v4.x; c0y += v0.y + v4.y;
    c1x += v1.x + v5.x; c1y += v1.y + v5.y;
    c2x += v2.x + v6.x; c2y += v2.y + v6.y;
    c3x += v3.x + v7.x; c3y += v3.y + v7.y;
  }
  for (; j < s1; ++j) {
    int i = csr[j];
    float2 v = x2[(size_t)i * 64 + lane];
    if (AFF) {
      v.x = fmaxf(fmaf(v.x, sc0, sh0), 0.f);
      v.y = fmaxf(fmaf(v.y, sc1, sh1), 0.f);
    }
    c0x += v.x; c0y += v.y;
  }
  float2 acc;
  acc.x = ax + ((c0x + c1x) + (c2x + c3x));
  acc.y = ay + ((c0y + c1y) + (c2y + c3y));
  ((float2*)outp)[(size_t)node * 64 + lane] = acc;
}

// C = f(A) @ W^T + b, with per-channel sum/sumsq atomics for BN.
__global__ __launch_bounds__(256) void gemm_gin_kernel(
    const float* __restrict__ A, const float* __restrict__ WT,
    const float* __restrict__ bias,
    const float* __restrict__ pre_scale, const float* __restrict__ pre_shift,
    float* __restrict__ C,
    float* __restrict__ ssum, float* __restrict__ ssq, int M) {
  __shared__ float As[64][132];
  __shared__ float Wt[128][68];
  int tid = threadIdx.x;
  int tx = tid & 15, ty = tid >> 4;
  int bx = blockIdx.x & 1, by = blockIdx.x >> 1;
  int row0 = by * 64, c0 = bx * 64;
#pragma unroll
  for (int i = 0; i < 8; ++i) {
    int slot = tid + i * 256;
    int r = slot >> 5, k4 = (slot & 31) << 2;
    float4 v = make_float4(0.f, 0.f, 0.f, 0.f);
    if (row0 + r < M) v = *(const float4*)(A + (size_t)(row0 + r) * 128 + k4);
    if (pre_scale) {
      v.x = fmaxf(fmaf(v.x, pre_scale[k4 + 0], pre_shift[k4 + 0]), 0.f);
      v.y = fmaxf(fmaf(v.y, pre_scale[k4 + 1], pre_shift[k4 + 1]), 0.f);
      v.z = fmaxf(fmaf(v.z, pre_scale[k4 + 2], pre_shift[k4 + 2]), 0.f);
      v.w = fmaxf(fmaf(v.w, pre_scale[k4 + 3], pre_shift[k4 + 3]), 0.f);
    }
    *(float4*)&As[r][k4] = v;
  }
#pragma unroll
  for (int i = 0; i < 8; ++i) {
    int slot = tid + i * 256;
    int k = slot >> 4, c4 = (slot & 15) << 2;
    *(float4*)&Wt[k][c4] = *(const float4*)(WT + (size_t)k * 128 + c0 + c4);
  }
  __syncthreads();
  float acc[4][4];
#pragma unroll
  for (int i = 0; i < 4; ++i)
#pragma unroll
    for (int j = 0; j < 4; ++j) acc[i][j] = 0.f;
#pragma unroll 4
  for (int kk = 0; kk < 128; kk += 4) {
    float4 w0 = *(const float4*)&Wt[kk + 0][tx << 2];
    float4 w1 = *(const float4*)&Wt[kk + 1][tx << 2];
    float4 w2 = *(const float4*)&Wt[kk + 2][tx << 2];
    float4 w3 = *(const float4*)&Wt[kk + 3][tx << 2];
#pragma unroll
    for (int i = 0; i < 4; ++i) {
      float4 a = *(const float4*)&As[(ty << 2) + i][kk];
      acc[i][0] += a.x * w0.x + a.y * w1.x + a.z * w2.x + a.w * w3.x;
      acc[i][1] += a.x * w0.y + a.y * w1.y + a.z * w2.y + a.w * w3.y;
      acc[i][2] += a.x * w0.z + a.y * w1.z + a.z * w2.z + a.w * w3.z;
      acc[i][3] += a.x * w0.w + a.y * w1.w + a.z * w2.w + a.w * w3.w;
    }
  }
  __syncthreads();
  float b0v = bias[c0 + (tx << 2) + 0];
  float b1v = bias[c0 + (tx << 2) + 1];
  float b2v = bias[c0 + (tx << 2) + 2];
  float b3v = bias[c0 + (tx << 2) + 3];
  float psum[4] = {0.f, 0.f, 0.f, 0.f}, psq[4] = {0.f, 0.f, 0.f, 0.f};
#pragma unroll
  for (int i = 0; i < 4; ++i) {
    int r = row0 + (ty << 2) + i;
    if (r < M) {
      float4 v;
      v.x = acc[i][0] + b0v; v.y = acc[i][1] + b1v;
      v.z = acc[i][2] + b2v; v.w = acc[i][3] + b3v;
      *(float4*)(C + (size_t)r * 128 + c0 + (tx << 2)) = v;
      psum[0] += v.x; psum[1] += v.y; psum[2] += v.z; psum[3] += v.w;
      psq[0] += v.x * v.x; psq[1] += v.y * v.y; psq[2] += v.z * v.z; psq[3] += v.w * v.w;
    }
  }
  float* red = &As[0][0];
#pragma unroll
  for (int j = 0; j < 4; ++j) {
    red[ty * 68 + (tx << 2) + j] = psum[j];
    red[1088 + ty * 68 + (tx << 2) + j] = psq[j];
  }
  __syncthreads();
  if (tid < 64) {
    float s = 0.f, sq = 0.f;
#pragma unroll
    for (int t = 0; t < 16; ++t) { s += red[t * 68 + tid]; sq += red[1088 + t * 68 + tid]; }
    atomicAdd(&ssum[c0 + tid], s);
    atomicAdd(&ssq[c0 + tid], sq);
  }
}

__global__ void bn_finalize_kernel(const float* __restrict__ sums, const float* __restrict__ sqs,
                                   const float* __restrict__ gamma, const float* __restrict__ beta,
                                   float* __restrict__ scale, float* __restrict__ shift) {
  int c = threadIdx.x;  // 128
  const float invN = 1.0f / (float)NN;
  float m = sums[c] * invN;
  float v = sqs[c] * invN - m * m;
  float rs = rsqrtf(v + 1e-5f);
  float sc = gamma[c] * rs;
  scale[c] = sc;
  shift[c] = beta[c] - m * sc;
}

// ---------------- Set2Set ----------------

__global__ __launch_bounds__(256) void lstm_cell_kernel(
    const float* __restrict__ inA, int pitchA, int splitK,
    const float* __restrict__ inB,
    const float* __restrict__ WT, const float* __restrict__ bias,
    float* __restrict__ cstate, float* __restrict__ hout, int K) {
  __shared__ float As[16][132];
  __shared__ float Wt[128][68];
  int tid = threadIdx.x;
  int tx = tid & 15, ty = tid >> 4;
  int bx = blockIdx.x, by = blockIdx.y;
  int row0 = by * 16, c0 = bx * 64;
  float acc[4] = {0.f, 0.f, 0.f, 0.f};
  for (int kc = 0; kc < K; kc += 128) {
#pragma unroll
    for (int i = 0; i < 2; ++i) {
      int slot = tid + i * 256;
      int r = slot >> 5, k4 = (slot & 31) << 2;
      int gc = kc + k4;
      const float* src = (gc < splitK) ? inA + (size_t)(row0 + r) * pitchA + gc
                                       : inB + (size_t)(row0 + r) * 128 + (gc - splitK);
      *(float4*)&As[r][k4] = *(const float4*)src;
    }
#pragma unroll
    for (int i = 0; i < 8; ++i) {
      int slot = tid + i * 256;
      int k = slot >> 4, c4 = (slot & 15) << 2;
      *(float4*)&Wt[k][c4] = *(const float4*)(WT + (size_t)(kc + k) * 512 + c0 + c4);
    }
    __syncthreads();
#pragma unroll 4
    for (int kk = 0; kk < 128; kk += 4) {
      float4 a = *(const float4*)&As[ty][kk];
      float4 w0 = *(const float4*)&Wt[kk + 0][tx << 2];
      float4 w1 = *(const float4*)&Wt[kk + 1][tx << 2];
      float4 w2 = *(const float4*)&Wt[kk + 2][tx << 2];
      float4 w3 = *(const float4*)&Wt[kk + 3][tx << 2];
      acc[0] += a.x * w0.x + a.y * w1.x + a.z * w2.x + a.w * w3.x;
      acc[1] += a.x * w0.y + a.y * w1.y + a.z * w2.y + a.w * w3.y;
      acc[2] += a.x * w0.z + a.y * w1.z + a.z * w2.z + a.w * w3.z;
      acc[3] += a.x * w0.w + a.y * w1.w + a.z * w2.w + a.w * w3.w;
    }
    __syncthreads();
  }
  int b = row0 + ty;
  int j = bx * 16 + tx;
  int ob = c0 + (tx << 2);
  float ii = acc[0] + bias[ob + 0];
  float ff = acc[1] + bias[ob + 1];
  float gg = acc[2] + bias[ob + 2];
  float oo = acc[3] + bias[ob + 3];
  float cp = cstate[b * 128 + j];
  float si = 1.f / (1.f + expf(-ii));
  float sf = 1.f / (1.f + expf(-ff));
  float so = 1.f / (1.f + expf(-oo));
  float cn = sf * cp + si * tanhf(gg);
  float hv = so * tanhf(cn);
  cstate[b * 128 + j] = cn;
  hout[b * 128 + j] = hv;
}

// per-graph segment softmax attention with fused BN affine+relu on x reads.
__global__ __launch_bounds__(256) void attention_kernel(
    const float* __restrict__ x, const int* __restrict__ gptr,
    const float* __restrict__ h3,
    const float* __restrict__ pre_scale, const float* __restrict__ pre_shift,
    float* __restrict__ ebuf, float* __restrict__ qstar) {
  int g = blockIdx.x;
  int tid = threadIdx.x;
  int lane = tid & 63, w = tid >> 6;
  __shared__ float xs[SEG_CAP * 128];
  __shared__ float es[SEG_CAP];
  __shared__ float q[128];
  __shared__ float wred[4];
  __shared__ float rpart[4][128];
  __shared__ float sm, ssv;
  if (tid < 128) q[tid] = h3[g * 128 + tid];
  __syncthreads();
  int s0 = gptr[g], s1 = gptr[g + 1];
  bool fit = (s1 - s0) <= SEG_CAP;
  const float2* x2 = (const float2*)x;
  float2 qv = ((const float2*)q)[lane];
  float sc0 = pre_scale[2 * lane], sc1 = pre_scale[2 * lane + 1];
  float sh0 = pre_shift[2 * lane], sh1 = pre_shift[2 * lane + 1];
  // pass 1: e + max (stage transformed x into LDS)
  float wmax = -3.0e38f;
  for (int n = s0 + w; n < s1; n += 4) {
    float2 v = x2[(size_t)n * 64 + lane];
    v.x = fmaxf(fmaf(v.x, sc0, sh0), 0.f);
    v.y = fmaxf(fmaf(v.y, sc1, sh1), 0.f);
    if (fit) {
      xs[(n - s0) * 128 + 2 * lane] = v.x;
      xs[(n - s0) * 128 + 2 * lane + 1] = v.y;
    }
    float e = v.x * qv.x + v.y * qv.y;
#pragma unroll
    for (int sh = 32; sh; sh >>= 1) e += __shfl_xor(e, sh);
    if (lane == 0) { if (fit) es[n - s0] = e; else ebuf[n] = e; }
    wmax = fmaxf(wmax, e);
  }
  if (lane == 0) wred[w] = wmax;
  __syncthreads();
  if (tid == 0) sm = fmaxf(fmaxf(wred[0], wred[1]), fmaxf(wred[2], wred[3]));
  __syncthreads();
  float m = sm;
  // pass 2: sum exp
  float loc = 0.f;
  for (int n = s0 + tid; n < s1; n += 256) {
    float e = fit ? es[n - s0] : ebuf[n];
    loc += expf(e - m);
  }
#pragma unroll
  for (int sh = 32; sh; sh >>= 1) loc += __shfl_xor(loc, sh);
  __syncthreads();
  if (lane == 0) wred[w] = loc;
  __syncthreads();
  if (tid == 0) ssv = wred[0] + wred[1] + wred[2] + wred[3];
  __syncthreads();
  float inv = 1.0f / ssv;
  // pass 3: r = sum a*x
  float rx = 0.f, ry = 0.f;
  for (int n = s0 + w; n < s1; n += 4) {
    float e = fit ? es[n - s0] : ebuf[n];
    float coef = expf(e - m) * inv;
    float vx, vy;
    if (fit) {
      vx = xs[(n - s0) * 128 + 2 * lane];
      vy = xs[(n - s0) * 128 + 2 * lane + 1];
    } else {
      float2 v = x2[(size_t)n * 64 + lane];
      vx = fmaxf(fmaf(v.x, sc0, sh0), 0.f);
      vy = fmaxf(fmaf(v.y, sc1, sh1), 0.f);
    }
    rx += coef * vx; ry += coef * vy;
  }
  rpart[w][2 * lane] = rx;
  rpart[w][2 * lane + 1] = ry;
  __syncthreads();
  if (tid < 128) {
    float r = rpart[0][tid] + rpart[1][tid] + rpart[2][tid] + rpart[3][tid];
    qstar[(size_t)g * 256 + tid] = q[tid];
    qstar[(size_t)g * 256 + 128 + tid] = r;
  }
}

__global__ void final_linear_kernel(const float* __restrict__ qstar, const float* __restrict__ WL,
                                    const float* __restrict__ bL, float* __restrict__ out) {
  int g = blockIdx.x;
  int lane = threadIdx.x;  // 64
  float a0 = 0.f, a1 = 0.f;
  for (int k = lane; k < 256; k += 64) {
    float qv = qstar[(size_t)g * 256 + k];
    a0 += qv * WL[k];
    a1 += qv * WL[256 + k];
  }
#pragma unroll
  for (int sh = 32; sh; sh >>= 1) {
    a0 += __shfl_xor(a0, sh);
    a1 += __shfl_xor(a1, sh);
  }
  if (lane == 0) {
    out[2 * g + 0] = a0 + bL[0];
    out[2 * g + 1] = a1 + bL[1];
  }
}

// ---------------- launch ----------------

extern "C" void kernel_launch(void* const* d_in, const int* in_sizes, int n_in,
                              void* d_out, int out_size, void* d_ws, size_t ws_size,
                              hipStream_t stream) {
  const float* x = (const float*)d_in[0];
  const int* ei = (const int*)d_in[1];
  const int* batch = (const int*)d_in[2];
  const float* gW[4]  = {(const float*)d_in[3],  (const float*)d_in[7],
                         (const float*)d_in[11], (const float*)d_in[15]};
  const float* gb[4]  = {(const float*)d_in[4],  (const float*)d_in[8],
                         (const float*)d_in[12], (const float*)d_in[16]};
  const float* gga[4] = {(const float*)d_in[5],  (const float*)d_in[9],
                         (const float*)d_in[13], (const float*)d_in[17]};
  const float* gbe[4] = {(const float*)d_in[6],  (const float*)d_in[10],
                         (const float*)d_in[14], (const float*)d_in[18]};
  const float* Wih0 = (const float*)d_in[19];
  const float* Whh0 = (const float*)d_in[20];
  const float* b0   = (const float*)d_in[21];
  const float* WihR = (const float*)d_in[22];
  const float* WhhR = (const float*)d_in[23];
  const float* bR   = (const float*)d_in[24];
  const float* linW = (const float*)d_in[25];
  const float* linb = (const float*)d_in[26];
  float* out = (float*)d_out;

  char* base = (char*)d_ws;
  size_t off = 0;
  auto allocf = [&](size_t n) { float* p = (float*)(base + off); off += n * sizeof(float); return p; };
  float* xa    = allocf(6400000);
  float* xb    = allocf(6400000);
  float* ginWT = allocf(65536);
  float* WT0   = allocf(196608);
  float* WTR   = allocf(393216);
  float* bc0   = allocf(512);
  float* bcR   = allocf(1536);
  float* ebuf  = allocf(50000);
  // ---- zero region (contiguous): 460800 floats = 115200 float4 ----
  float* stats = allocf(1024);
  float* sshf  = allocf(1024);
  float* cbuf  = allocf(131072);
  float* hbuf  = allocf(262144);
  float* qstar = allocf(65536);
  // ---- ints (all fully written before read; no zeroing needed) ----
  int* row_start = (int*)(base + off); off += 50004 * 4;
  int* gptr = (int*)(base + off); off += 260 * 4;
  int* csr = (int*)(base + off); off += 800000 * 4;
  int* packed = (int*)(base + off); off += 800000 * 4;
  int* partial = (int*)(base + off); off += NBIN * NBLK * 4;
  int* block_base = (int*)(base + off); off += NBIN * NBLK * 4;
  int* total = (int*)(base + off); off += 256 * 4;
  int* coarse_base = (int*)(base + off); off += 260 * 4;
  (void)ws_size; (void)in_sizes; (void)n_in; (void)out_size;

  // prep
  zero4_kernel<<<450, 256, 0, stream>>>((float4*)stats, 115200);
  gptr_boundary_kernel<<<196, 256, 0, stream>>>(batch, gptr);
  coarse_hist_kernel<<<NBLK, 256, 0, stream>>>(ei, partial);
  scan_partials_kernel<<<NBIN, 256, 0, stream>>>(partial, block_base, total);
  scan_totals_kernel<<<1, 256, 0, stream>>>(total, coarse_base);
  bucket_scatter_kernel<<<NBLK, 256, 0, stream>>>(ei, coarse_base, block_base, packed);
  csr_finalize_kernel<<<NBIN, 256, 0, stream>>>(packed, coarse_base, row_start, csr);
  prep_weights_kernel<<<2568, 256, 0, stream>>>(gW[0], gW[1], gW[2], gW[3], Wih0, Whh0,
                                                WihR, WhhR, b0, bR, ginWT, WT0, WTR, bc0, bcR);

  // GIN layer 1
  gin_agg_kernel<false><<<12500, 256, 0, stream>>>(x, row_start, csr, nullptr, nullptr, xb);
  gemm_gin_kernel<<<1564, 256, 0, stream>>>(xb, ginWT + 0 * 16384, gb[0], nullptr, nullptr,
                                            xa, stats + 0, stats + 128, NN);
  bn_finalize_kernel<<<1, 128, 0, stream>>>(stats + 0, stats + 128, gga[0], gbe[0], sshf + 0, sshf + 128);
  gemm_gin_kernel<<<1564, 256, 0, stream>>>(xa, ginWT + 1 * 16384, gb[1], sshf + 0, sshf + 128,
                                            xb, stats + 256, stats + 384, NN);
  bn_finalize_kernel<<<1, 128, 0, stream>>>(stats + 256, stats + 384, gga[1], gbe[1], sshf + 256, sshf + 384);
  // GIN layer 2 (BN2 fused into the gather)
  gin_agg_kernel<true><<<12500, 256, 0, stream>>>(xb, row_start, csr, sshf + 256, sshf + 384, xa);
  gemm_gin_kernel<<<1564, 256, 0, stream>>>(xa, ginWT + 2 * 16384, gb[2], nullptr, nullptr,
                                            xb, stats + 512, stats + 640, NN);
  bn_finalize_kernel<<<1, 128, 0, stream>>>(stats + 512, stats + 640, gga[2], gbe[2], sshf + 512, sshf + 640);
  gemm_gin_kernel<<<1564, 256, 0, stream>>>(xb, ginWT + 3 * 16384, gb[3], sshf + 512, sshf + 640,
                                            xa, stats + 768, stats + 896, NN);
  bn_finalize_kernel<<<1, 128, 0, stream>>>(stats + 768, stats + 896, gga[3], gbe[3], sshf + 768, sshf + 896);
  // xa holds pre-BN4 features; BN4 affine+relu fused into attention reads

  // Set2Set
  dim3 lg(8, 16);
  for (int step = 0; step < 4; ++step) {
    int p = step & 1, pq = 1 - p;
    float* h0r = hbuf + (size_t)(0 * 2 + p) * 32768;  float* h0w = hbuf + (size_t)(0 * 2 + pq) * 32768;
    float* h1r = hbuf + (size_t)(1 * 2 + p) * 32768;  float* h1w = hbuf + (size_t)(1 * 2 + pq) * 32768;
    float* h2r = hbuf + (size_t)(2 * 2 + p) * 32768;  float* h2w = hbuf + (size_t)(2 * 2 + pq) * 32768;
    float* h3r = hbuf + (size_t)(3 * 2 + p) * 32768;  float* h3w = hbuf + (size_t)(3 * 2 + pq) * 32768;
    lstm_cell_kernel<<<lg, 256, 0, stream>>>(qstar, 256, 256, h0r, WT0, bc0, cbuf + 0, h0w, 384);
    lstm_cell_kernel<<<lg, 256, 0, stream>>>(h0w, 128, 128, h1r, WTR + 0, bcR + 0, cbuf + 32768, h1w, 256);
    lstm_cell_kernel<<<lg, 256, 0, stream>>>(h1w, 128, 128, h2r, WTR + 131072, bcR + 512, cbuf + 65536, h2w, 256);
    lstm_cell_kernel<<<lg, 256, 0, stream>>>(h2w, 128, 128, h3r, WTR + 262144, bcR + 1024, cbuf + 98304, h3w, 256);
    attention_kernel<<<256, 256, 0, stream>>>(xa, gptr, h3w, sshf + 768, sshf + 896, ebuf, qstar);
  }
  final_linear_kernel<<<256, 64, 0, stream>>>(qstar, linW, linb, out);
}